// Round 15
// baseline (326.413 us; speedup 1.0000x reference)
//
#include <hip/hip_runtime.h>
#include <math.h>

constexpr int B_ = 2, N_ = 1024, D_ = 384, H_ = 8, HD_ = 48, DFF2 = 512, L_ = 4;
constexpr int BN_ = B_ * N_;                       // 2048 rows
constexpr size_t NNs = (size_t)N_ * N_;            // 1048576
constexpr size_t BNNc = (size_t)B_ * N_ * N_;      // 2097152
constexpr int JT = 64, NSPLIT = 4;
constexpr int CCLD = 448;                          // cc row stride (387 padded to 7*64)
constexpr float RSCALE = 0.14433756729740643f;     // 1/sqrt(48)

typedef short bf16x8 __attribute__((ext_vector_type(8)));
typedef float f32x4 __attribute__((ext_vector_type(4)));

__device__ inline float wsum(float v) {
#pragma unroll
  for (int m = 32; m; m >>= 1) v += __shfl_xor(v, m, 64);
  return v;
}
__device__ inline float b2f(unsigned int s) {
  union { unsigned int u; float f; } v; v.u = s << 16; return v.f;
}
__device__ inline unsigned short f2b(float f) {
  union { float f; unsigned int u; } v; v.f = f;
  unsigned int r = v.u + 0x7fffu + ((v.u >> 16) & 1u);
  return (unsigned short)(r >> 16);
}

// ---------------------------------------------------------------- misc: copy x + pad-zero qp/kpf + pack bias
__global__ __launch_bounds__(256) void misc_kernel(float* __restrict__ x,
                                                   const float* __restrict__ x_rigid,
                                                   unsigned short* __restrict__ qp,
                                                   unsigned short* __restrict__ kpf,
                                                   const float* __restrict__ bq,
                                                   const float* __restrict__ bk,
                                                   const float* __restrict__ bv,
                                                   float* __restrict__ bqkv) {
  int gid = blockIdx.x * 256 + threadIdx.x;
  if (gid < 786432) { x[gid] = x_rigid[gid]; return; }
  gid -= 786432;
  if (gid < 262144) {
    int r = gid >> 7, rem = gid & 127;
    int h = rem >> 4, c = rem & 15;
    qp[(size_t)r * 512 + h * 64 + 48 + c] = 0;
    return;
  }
  gid -= 262144;
  if (gid < 262144) {
    int fh = gid >> 8, rem = gid & 255;
    kpf[(size_t)fh * 1024 + 768 + rem] = 0;
    return;
  }
  gid -= 262144;
  if (gid < L_ * 1152) {
    int l = gid / 1152, n = gid % 1152;
    bqkv[gid] = (n < 384) ? bq[l * D_ + n] : (n < 768) ? bk[l * D_ + n - 384] : bv[l * D_ + n - 768];
  }
}

// ---------------------------------------------------------------- unified weight pack (all 6 transposes, 1 dispatch)
__global__ __launch_bounds__(256) void pack_all_kernel(
    const float* __restrict__ Wq, const float* __restrict__ Wk, const float* __restrict__ Wv,
    const float* __restrict__ Wfc, const float* __restrict__ Wff1, const float* __restrict__ Wff2,
    unsigned short* __restrict__ WqkvT, unsigned short* __restrict__ WfcT,
    unsigned short* __restrict__ Wff1T, unsigned short* __restrict__ Wff2T) {
  __shared__ float ts[32][33];
  const int bid = blockIdx.x;
  const int lz = blockIdx.z;
  const int t = threadIdx.x;
  const float* in;
  unsigned short* out;
  size_t istr, ostr;
  int K, Nc, Kpad, n0, k0;
  if (bid < 432) {  // Wq/Wk/Wv: 3 x (12x12)
    int which = bid / 144, r = bid % 144;
    n0 = (r % 12) * 32; k0 = (r / 12) * 32;
    in = (which == 0) ? Wq : (which == 1) ? Wk : Wv;
    istr = (size_t)D_ * D_;
    out = WqkvT + (size_t)which * 384 * 384;
    ostr = (size_t)1152 * D_;
    K = D_; Nc = D_; Kpad = D_;
  } else if (bid < 600) {  // Wfc: 12x14
    int r = bid - 432;
    n0 = (r % 12) * 32; k0 = (r / 12) * 32;
    in = Wfc; istr = (size_t)387 * D_;
    out = WfcT; ostr = (size_t)D_ * CCLD;
    K = 387; Nc = D_; Kpad = CCLD;
  } else if (bid < 792) {  // Wff1: 16x12
    int r = bid - 600;
    n0 = (r % 16) * 32; k0 = (r / 16) * 32;
    in = Wff1; istr = (size_t)D_ * DFF2;
    out = Wff1T; ostr = (size_t)DFF2 * D_;
    K = D_; Nc = DFF2; Kpad = D_;
  } else {  // Wff2: 12x16
    int r = bid - 792;
    n0 = (r % 12) * 32; k0 = (r / 12) * 32;
    in = Wff2; istr = (size_t)DFF2 * D_;
    out = Wff2T; ostr = (size_t)D_ * DFF2;
    K = DFF2; Nc = D_; Kpad = DFF2;
  }
  const float* inl = in + (size_t)lz * istr;
  unsigned short* outl = out + (size_t)lz * ostr;
#pragma unroll
  for (int u = 0; u < 4; ++u) {
    int i = t + u * 256, kk = i >> 5, nn = i & 31;
    int k = k0 + kk;
    ts[kk][nn] = (k < K) ? inl[(size_t)k * Nc + n0 + nn] : 0.f;
  }
  __syncthreads();
#pragma unroll
  for (int u = 0; u < 4; ++u) {
    int i = t + u * 256, nn = i >> 5, kk = i & 31;
    outl[(size_t)(n0 + nn) * Kpad + k0 + kk] = f2b(ts[kk][nn]);
  }
}

// ---------------------------------------------------------------- RBF-only precompute: 4 pairs/thread (dist/mask -> db4)
__global__ __launch_bounds__(256) void rbf4v_kernel(const float* __restrict__ dist,
                                                    const int* __restrict__ mask,
                                                    const float* __restrict__ Wmlp,
                                                    const float* __restrict__ bmlp,
                                                    unsigned short* __restrict__ db4) {
  size_t i4 = ((size_t)blockIdx.x * 256 + threadIdx.x) * 4;  // grid covers BNNc/4 exactly
  if (i4 >= BNNc) return;
  float4 dv4 = *reinterpret_cast<const float4*>(dist + i4);
  int4 mk4 = *reinterpret_cast<const int4*>(mask + i4);
  float dvs[4] = {dv4.x, dv4.y, dv4.z, dv4.w};
  int mks[4] = {mk4.x, mk4.y, mk4.z, mk4.w};
  float sv[4][4];  // [elem][layer]
#pragma unroll
  for (int e = 0; e < 4; ++e) {
    float rb[16];
#pragma unroll
    for (int r = 0; r < 16; ++r) {
      float tt = (dvs[e] - (float)r * (20.0f / 15.0f)) * 0.8f;
      rb[r] = __expf(-tt * tt);
    }
#pragma unroll
    for (int l2 = 0; l2 < L_; ++l2) {
      float s = bmlp[l2];
#pragma unroll
      for (int r = 0; r < 16; ++r) s += rb[r] * Wmlp[l2 * 16 + r];
      sv[e][l2] = s;
    }
  }
#pragma unroll
  for (int l2 = 0; l2 < L_; ++l2) {
    unsigned int lo = (unsigned int)f2b(mks[0] == 0 ? -1e9f : sv[0][l2]) |
                      ((unsigned int)f2b(mks[1] == 0 ? -1e9f : sv[1][l2]) << 16);
    unsigned int hi = (unsigned int)f2b(mks[2] == 0 ? -1e9f : sv[2][l2]) |
                      ((unsigned int)f2b(mks[3] == 0 ? -1e9f : sv[3][l2]) << 16);
    uint2 w; w.x = lo; w.y = hi;
    *reinterpret_cast<uint2*>(&db4[(size_t)l2 * BNNc + i4]) = w;
  }
}
// per-layer fallback (small workspace)
__global__ __launch_bounds__(256) void rbf_kernel(const float* __restrict__ dist,
                                                  const int* __restrict__ mask,
                                                  const float* __restrict__ wm,
                                                  const float* __restrict__ bm,
                                                  unsigned short* __restrict__ dbias) {
  size_t i = (size_t)blockIdx.x * 256 + threadIdx.x;
  size_t stride = (size_t)gridDim.x * 256;
  float w[16];
#pragma unroll
  for (int r = 0; r < 16; ++r) w[r] = wm[r];
  float b0 = bm[0];
  for (; i < BNNc; i += stride) {
    float dv = dist[i];
    float sv = b0;
#pragma unroll
    for (int r = 0; r < 16; ++r) {
      float tt = (dv - (float)r * (20.0f / 15.0f)) * 0.8f;
      sv += __expf(-tt * tt) * w[r];
    }
    dbias[i] = f2b((mask[i] == 0) ? -1e9f : sv);
  }
}

// ---------------------------------------------------------------- layernorm (wave per row, bf16 out), optional fused v3d
template <bool V3D>
__global__ __launch_bounds__(256) void ln_kernel(const float* __restrict__ x,
                                                 const float* __restrict__ g,
                                                 const float* __restrict__ b,
                                                 unsigned short* __restrict__ out,
                                                 const float* __restrict__ W3,
                                                 const float* __restrict__ b3,
                                                 float* __restrict__ v3d) {
  int lane = threadIdx.x & 63, wid = threadIdx.x >> 6;
  int row = blockIdx.x * 4 + wid;
  const float* xp = x + (size_t)row * D_;
  float v[6], s = 0.f, s2 = 0.f;
#pragma unroll
  for (int i = 0; i < 6; ++i) {
    v[i] = xp[lane + i * 64];
    s += v[i]; s2 += v[i] * v[i];
  }
  s = wsum(s); s2 = wsum(s2);
  float mean = s * (1.0f / D_);
  float var = s2 * (1.0f / D_) - mean * mean;
  float rstd = rsqrtf(var + 1e-5f);
  unsigned short* op = out + (size_t)row * D_;
  float a0 = 0.f, a1 = 0.f, a2 = 0.f;
#pragma unroll
  for (int i = 0; i < 6; ++i) {
    int d = lane + i * 64;
    float nv = (v[i] - mean) * rstd * g[d] + b[d];
    op[d] = f2b(nv);
    if (V3D) {
      a0 += nv * W3[d * 3 + 0];
      a1 += nv * W3[d * 3 + 1];
      a2 += nv * W3[d * 3 + 2];
    }
  }
  if (V3D) {
    a0 = wsum(a0); a1 = wsum(a1); a2 = wsum(a2);
    if (lane == 0) {
      v3d[row * 3 + 0] = a0 + b3[0];
      v3d[row * 3 + 1] = a1 + b3[1];
      v3d[row * 3 + 2] = a2 + b3[2];
    }
  }
}

// ---------------------------------------------------------------- bf16 MFMA GEMM v3: double-buffered LDS, 1 barrier/K-step
// Tile: BM=64 x BN=32 x BK=64. EPI 0: qkv (q dense, k/v frag-major); 1: fp32 += ; 2: relu->bf16.
template <int EPI>
__global__ __launch_bounds__(256) void mfma_gemm2(const unsigned short* __restrict__ A, int lda,
                                                  const unsigned short* __restrict__ WT, int ldw,
                                                  const float* __restrict__ bias,
                                                  float* __restrict__ C0, float* __restrict__ C1,
                                                  float* __restrict__ C2, int ldc, int K) {
  __shared__ __align__(16) unsigned short As[2][64 * 72];
  __shared__ __align__(16) unsigned short Bs[2][32 * 72];
  const int t = threadIdx.x;
  const int l = t & 63, w = t >> 6;
  const int lr = l & 15, lk = l >> 4;
  const int n0 = blockIdx.x * 32, m0 = blockIdx.y * 64;
  const int wm = (w & 1) * 32, wn = (w >> 1) * 16;
  const int arow = t >> 3, acol8 = (t & 7) * 8;
  uint4 ra0, ra1, rb;
  const unsigned short* pa0 = A + (size_t)(m0 + arow) * lda + acol8;
  const unsigned short* pa1 = A + (size_t)(m0 + arow + 32) * lda + acol8;
  const unsigned short* pb = WT + (size_t)(n0 + arow) * ldw + acol8;
  ra0 = *reinterpret_cast<const uint4*>(pa0);
  ra1 = *reinterpret_cast<const uint4*>(pa1);
  rb = *reinterpret_cast<const uint4*>(pb);
  f32x4 acc[2] = {};
  int p = 0;
  for (int kt = 0; kt < K; kt += 64) {
    *reinterpret_cast<uint4*>(&As[p][arow * 72 + acol8]) = ra0;
    *reinterpret_cast<uint4*>(&As[p][(arow + 32) * 72 + acol8]) = ra1;
    *reinterpret_cast<uint4*>(&Bs[p][arow * 72 + acol8]) = rb;
    if (kt + 64 < K) {
      ra0 = *reinterpret_cast<const uint4*>(pa0 + kt + 64);
      ra1 = *reinterpret_cast<const uint4*>(pa1 + kt + 64);
      rb = *reinterpret_cast<const uint4*>(pb + kt + 64);
    }
    __syncthreads();
#pragma unroll
    for (int ks = 0; ks < 2; ++ks) {
      bf16x8 av0 = *reinterpret_cast<const bf16x8*>(&As[p][(wm + lr) * 72 + ks * 32 + lk * 8]);
      bf16x8 av1 = *reinterpret_cast<const bf16x8*>(&As[p][(wm + 16 + lr) * 72 + ks * 32 + lk * 8]);
      bf16x8 bv = *reinterpret_cast<const bf16x8*>(&Bs[p][(wn + lr) * 72 + ks * 32 + lk * 8]);
      acc[0] = __builtin_amdgcn_mfma_f32_16x16x32_bf16(av0, bv, acc[0], 0, 0, 0);
      acc[1] = __builtin_amdgcn_mfma_f32_16x16x32_bf16(av1, bv, acc[1], 0, 0, 0);
    }
    p ^= 1;
  }
#pragma unroll
  for (int mi = 0; mi < 2; ++mi)
#pragma unroll
    for (int e = 0; e < 4; ++e) {
      int row = m0 + wm + mi * 16 + lk * 4 + e;
      int col = n0 + wn + lr;
      float v = acc[mi][e] + bias[col];
      if (EPI == 0) {
        if (col < 384) {
          int h = col / 48, hd = col - h * 48;
          ((unsigned short*)C0)[(size_t)row * 512 + h * 64 + hd] = f2b(v * RSCALE);
        } else if (col < 768) {
          int c2 = col - 384;
          int h = c2 / 48, d = c2 - h * 48;
          int b2 = row >> 10, j = row & 1023;
          int jb = j >> 4, jr = j & 15;
          int ks = d >> 5, dd = d & 31;
          size_t fid = (((size_t)(b2 * 64 + jb) * 8 + h) << 1) + ks;
          ((unsigned short*)C1)[fid * 512 + (size_t)(jr + ((dd >> 3) << 4)) * 8 + (d & 7)] = f2b(v);
        } else {
          int d = col - 768;
          int b2 = row >> 10, j = row & 1023;
          int jg = j >> 5, df = d >> 4;
          size_t fid = (size_t)(b2 * 32 + jg) * 24 + df;
          ((unsigned short*)C2)[fid * 512 + (size_t)((d & 15) + (((j & 31) >> 3) << 4)) * 8 + (j & 7)] = f2b(v);
        }
      }
      if (EPI == 1) C0[(size_t)row * ldc + col] += v;
      if (EPI == 2) ((unsigned short*)C0)[(size_t)row * ldc + col] = f2b(fmaxf(v, 0.f));
    }
}

// ---------------------------------------------------------------- MFMA fused attention v9
// GMODE 0: layer 0 — compute G from ori/ad (fp32), use for frame term, store bf16 Ga/Gz.
// GMODE 1: layers 1-3 — read precomputed Ga/Gz (tile-top prefetch).
// GMODE 2: fallback — compute from ori/ad, no store.
template <int GMODE>
__global__ __launch_bounds__(512, 4) void attn16_kernel(
    const unsigned short* __restrict__ qp, const unsigned short* __restrict__ kpf,
    const unsigned short* __restrict__ vf, const unsigned short* __restrict__ db_l,
    uint2* __restrict__ Ga, unsigned int* __restrict__ Gz,
    const float* __restrict__ ad, const float* __restrict__ ori,
    const float* __restrict__ v3d,
    unsigned short* __restrict__ pO, float* __restrict__ pM, float* __restrict__ pL,
    float* __restrict__ pF, float* __restrict__ pMg, float* __restrict__ pLg) {
  __shared__ __align__(16) unsigned short pbuf[8 * 16 * 72];  // P bf16 [h][r][72] (wave-local rows)
  __shared__ __align__(16) unsigned short msw[8 * 16 * 68];   // per-head partials bf16; plane 0 reused for merged probs
  __shared__ __align__(16) float dbs[16 * 68];                // dbias tile (f32 after convert)
  __shared__ float fg_s[16];

  const int t = threadIdx.x;
  const int wv = t >> 6, l = t & 63;  // wv = head
  const int lr = l & 15, lk = l >> 4;
  const int sgrp = blockIdx.y;
  const int i0 = blockIdx.x * 16;
  const int b = i0 >> 10, ib = i0 & 1023;
  const int mr = t >> 5, mc = t & 31;  // merged softmax role: 32 threads per row

  const bf16x8 qf0 = *reinterpret_cast<const bf16x8*>(
      qp + (size_t)(i0 + lr) * 512 + wv * 64 + lk * 8);
  const bf16x8 qf1 = *reinterpret_cast<const bf16x8*>(
      qp + (size_t)(i0 + lr) * 512 + wv * 64 + 32 + lk * 8);

  f32x4 Ofr[3] = {};
  float fracc[2][3] = {};
  float m_ph[4], l_ph[4], fhv[4];
#pragma unroll
  for (int e = 0; e < 4; ++e) { m_ph[e] = -INFINITY; l_ph[e] = 0.f; }
  float m_mg = -INFINITY, l_mg = 0.f;

  for (int jt = sgrp * (N_ / NSPLIT); jt < (sgrp + 1) * (N_ / NSPLIT); jt += JT) {
    // ---- tile-top prefetch (GMODE 1): frame geometry for THIS tile ----
    uint2 ga_r0, ga_r1;
    unsigned int gz_r0, gz_r1;
    float w0p = 0.f, w1p = 0.f, w2p = 0.f;
    if (GMODE == 1) {
      const float* vp = v3d + (size_t)((b << 10) + jt + l) * 3;
      w0p = vp[0]; w1p = vp[1]; w2p = vp[2];
      size_t pij0 = ((size_t)b * N_ + (ib + wv * 2)) * N_ + jt + l;
      ga_r0 = Ga[pij0];
      gz_r0 = Gz[pij0];
      ga_r1 = Ga[pij0 + N_];
      gz_r1 = Gz[pij0 + N_];
    }
    // ---- Phase 1: stage dbias (bf16 -> f32), QK^T MFMA (coalesced frag loads) ----
    if (t < 128) {
      int r = t >> 3, c4 = t & 7;
      const uint4* src = reinterpret_cast<const uint4*>(
                             db_l + (size_t)b * NNs + (size_t)(ib + r) * N_ + jt) + c4;
      uint4 v = *src;
      float* dp = &dbs[r * 68 + c4 * 8];
      dp[0] = b2f(v.x & 0xffffu); dp[1] = b2f(v.x >> 16);
      dp[2] = b2f(v.y & 0xffffu); dp[3] = b2f(v.y >> 16);
      dp[4] = b2f(v.z & 0xffffu); dp[5] = b2f(v.z >> 16);
      dp[6] = b2f(v.w & 0xffffu); dp[7] = b2f(v.w >> 16);
    }
    f32x4 sc[4];
    {
      const unsigned short* kbase =
          kpf + ((((size_t)(b * 64) + (jt >> 4)) * 8 + wv) * 2 * 64 + l) * 8;
      bf16x8 kf0[4], kf1[4];
#pragma unroll
      for (int nj = 0; nj < 4; ++nj) {
        kf0[nj] = *reinterpret_cast<const bf16x8*>(kbase + (size_t)nj * 16 * 512);
        kf1[nj] = *reinterpret_cast<const bf16x8*>(kbase + (size_t)nj * 16 * 512 + 512);
      }
#pragma unroll
      for (int nj = 0; nj < 4; ++nj) {
        f32x4 acc = {};
        acc = __builtin_amdgcn_mfma_f32_16x16x32_bf16(qf0, kf0[nj], acc, 0, 0, 0);
        acc = __builtin_amdgcn_mfma_f32_16x16x32_bf16(qf1, kf1[nj], acc, 0, 0, 0);
        sc[nj] = acc;
      }
    }
#pragma unroll
    for (int nj = 0; nj < 4; ++nj)
#pragma unroll
      for (int e = 0; e < 4; ++e)
        msw[(wv * 16 + lk * 4 + e) * 68 + nj * 16 + lr] = f2b(sc[nj][e]);
    __syncthreads();
    // ---- Phase 2a: per-head softmax in registers, defer-max THR=8 ----
    bool needO;
    {
      float sv[4][4];
#pragma unroll
      for (int nj = 0; nj < 4; ++nj)
#pragma unroll
        for (int e = 0; e < 4; ++e)
          sv[nj][e] = sc[nj][e] + dbs[(lk * 4 + e) * 68 + nj * 16 + lr];
      float lm[4];
      bool need = false;
#pragma unroll
      for (int e = 0; e < 4; ++e) {
        lm[e] = fmaxf(fmaxf(sv[0][e], sv[1][e]), fmaxf(sv[2][e], sv[3][e]));
        need = need || (lm[e] > m_ph[e] + 8.f);
      }
      needO = __any(need);
      if (needO) {
#pragma unroll
        for (int e = 0; e < 4; ++e) {
          float rm = lm[e];
          rm = fmaxf(rm, __shfl_xor(rm, 1, 64));
          rm = fmaxf(rm, __shfl_xor(rm, 2, 64));
          rm = fmaxf(rm, __shfl_xor(rm, 4, 64));
          rm = fmaxf(rm, __shfl_xor(rm, 8, 64));
          float nm = fmaxf(m_ph[e], rm);
          fhv[e] = __expf(m_ph[e] - nm);
          m_ph[e] = nm;
          l_ph[e] *= fhv[e];
        }
      }
#pragma unroll
      for (int e = 0; e < 4; ++e) {
        float ls = 0.f;
#pragma unroll
        for (int nj = 0; nj < 4; ++nj) {
          float pv = __expf(sv[nj][e] - m_ph[e]);
          sv[nj][e] = pv;
          ls += pv;
        }
        ls += __shfl_xor(ls, 1, 64);
        ls += __shfl_xor(ls, 2, 64);
        ls += __shfl_xor(ls, 4, 64);
        ls += __shfl_xor(ls, 8, 64);
        l_ph[e] += ls;
#pragma unroll
        for (int nj = 0; nj < 4; ++nj)
          pbuf[(wv * 16 + lk * 4 + e) * 72 + nj * 16 + lr] = f2b(sv[nj][e]);
      }
    }
    // ---- Phase 2b: merged softmax (sum 8 bf16 planes + 8*dbias), defer-max ----
    {
      float mv[2];
#pragma unroll
      for (int i = 0; i < 2; ++i) {
        int j = mc + 32 * i;
        float s = 8.f * dbs[mr * 68 + j];
#pragma unroll
        for (int h = 0; h < 8; ++h) s += b2f(msw[(h * 16 + mr) * 68 + j]);
        mv[i] = s;
      }
      float lm2 = fmaxf(mv[0], mv[1]);
      bool needm = __any(lm2 > m_mg + 8.f);
      if (needm) {
        float tmax = lm2;
        tmax = fmaxf(tmax, __shfl_xor(tmax, 1, 64));
        tmax = fmaxf(tmax, __shfl_xor(tmax, 2, 64));
        tmax = fmaxf(tmax, __shfl_xor(tmax, 4, 64));
        tmax = fmaxf(tmax, __shfl_xor(tmax, 8, 64));
        tmax = fmaxf(tmax, __shfl_xor(tmax, 16, 64));
        float nm = fmaxf(m_mg, tmax);
        float f = __expf(m_mg - nm);
        m_mg = nm;
        l_mg *= f;
        if (mc == 0) fg_s[mr] = f;
      } else if (mc == 0) {
        fg_s[mr] = 1.f;
      }
      float lsum = 0.f;
#pragma unroll
      for (int i = 0; i < 2; ++i) {
        mv[i] = __expf(mv[i] - m_mg);
        lsum += mv[i];
        msw[mr * 68 + mc + 32 * i] = f2b(mv[i]);
      }
      lsum += __shfl_xor(lsum, 1, 64);
      lsum += __shfl_xor(lsum, 2, 64);
      lsum += __shfl_xor(lsum, 4, 64);
      lsum += __shfl_xor(lsum, 8, 64);
      lsum += __shfl_xor(lsum, 16, 64);
      l_mg += lsum;
    }
    // ---- Phase 3 (no barrier needed: all reads wave-local): PV MFMA + frame ----
    {
      bf16x8 af0 = *reinterpret_cast<const bf16x8*>(&pbuf[(wv * 16 + lr) * 72 + lk * 8]);
      bf16x8 af1 = *reinterpret_cast<const bf16x8*>(&pbuf[(wv * 16 + lr) * 72 + 32 + lk * 8]);
      const unsigned short* vbase =
          vf + ((((size_t)(b * 32) + (jt >> 5)) * 24 + wv * 3) * 64 + l) * 8;
#pragma unroll
      for (int ni = 0; ni < 3; ++ni) {
        bf16x8 bf0 = *reinterpret_cast<const bf16x8*>(vbase + (size_t)ni * 512);
        bf16x8 bf1 = *reinterpret_cast<const bf16x8*>(vbase + (size_t)(24 + ni) * 512);
        f32x4 o = Ofr[ni];
        if (needO) {
#pragma unroll
          for (int e = 0; e < 4; ++e) o[e] *= fhv[e];
        }
        o = __builtin_amdgcn_mfma_f32_16x16x32_bf16(af0, bf0, o, 0, 0, 0);
        o = __builtin_amdgcn_mfma_f32_16x16x32_bf16(af1, bf1, o, 0, 0, 0);
        Ofr[ni] = o;
      }
    }
    {
      float w0, w1, w2;
      if (GMODE == 1) {
        w0 = w0p; w1 = w1p; w2 = w2p;
      } else {
        const float* vp = v3d + (size_t)((b << 10) + jt + l) * 3;
        w0 = vp[0]; w1 = vp[1]; w2 = vp[2];
      }
#pragma unroll
      for (int e = 0; e < 2; ++e) {
        int r = wv * 2 + e;
        float pm = b2f(msw[r * 68 + l]);
        float d0, d1, d2;
        if (GMODE == 1) {
          uint2 ga = (e == 0) ? ga_r0 : ga_r1;
          unsigned int gz = (e == 0) ? gz_r0 : gz_r1;
          float g0 = b2f(ga.x & 0xffffu), g1 = b2f(ga.x >> 16);
          float g2 = b2f(ga.y & 0xffffu), g3 = b2f(ga.y >> 16);
          float g4 = b2f(gz & 0xffffu), g5 = b2f(gz >> 16);
          d0 = g0 * w2 - g1 * w1;
          d1 = g2 * w0 - g3 * w2;
          d2 = g4 * w1 - g5 * w0;
        } else {
          size_t pij = ((size_t)b * N_ + (ib + r)) * N_ + jt + l;
          const float* op = ori + pij * 9;
          const float* ap = ad + pij * 3;
          float a0 = ap[0], a1 = ap[1], a2 = ap[2];
          float c0 = op[0] + op[3] + op[6];
          float c1 = op[1] + op[4] + op[7];
          float c2 = op[2] + op[5] + op[8];
          float g0 = a1 * c2, g1 = a2 * c1, g2 = a2 * c0;
          float g3 = a0 * c2, g4 = a0 * c1, g5 = a1 * c0;
          d0 = g0 * w2 - g1 * w1;
          d1 = g2 * w0 - g3 * w2;
          d2 = g4 * w1 - g5 * w0;
          if (GMODE == 0) {
            uint2 oa;
            oa.x = (unsigned int)f2b(g0) | ((unsigned int)f2b(g1) << 16);
            oa.y = (unsigned int)f2b(g2) | ((unsigned int)f2b(g3) << 16);
            Ga[pij] = oa;
            Gz[pij] = (unsigned int)f2b(g4) | ((unsigned int)f2b(g5) << 16);
          }
        }
        float fgr = fg_s[r];
        fracc[e][0] = fracc[e][0] * fgr + pm * d0;
        fracc[e][1] = fracc[e][1] * fgr + pm * d1;
        fracc[e][2] = fracc[e][2] * fgr + pm * d2;
      }
    }
    __syncthreads();
  }
  // ---- epilogue: write split partials (O in bf16) ----
  const size_t rowb = (size_t)sgrp * BN_ + i0;
#pragma unroll
  for (int ni = 0; ni < 3; ++ni)
#pragma unroll
    for (int e = 0; e < 4; ++e)
      pO[(rowb + lk * 4 + e) * D_ + wv * 48 + ni * 16 + lr] = f2b(Ofr[ni][e]);
#pragma unroll
  for (int e = 0; e < 2; ++e)
#pragma unroll
    for (int c = 0; c < 3; ++c) {
      float v = wsum(fracc[e][c]);
      if (l == 0) pF[(rowb + wv * 2 + e) * 3 + c] = v;
    }
  if (lr == 0) {
#pragma unroll
    for (int e = 0; e < 4; ++e) {
      pM[(rowb + lk * 4 + e) * H_ + wv] = m_ph[e];
      pL[(rowb + lk * 4 + e) * H_ + wv] = l_ph[e];
    }
  }
  if (mc == 0) { pMg[rowb + mr] = m_mg; pLg[rowb + mr] = l_mg; }
}

// ---------------------------------------------------------------- combine split partials -> cc (bf16, padded)
constexpr int QR = 8;
__global__ __launch_bounds__(256) void combine_kernel(
    const unsigned short* __restrict__ pO, const float* __restrict__ pM,
    const float* __restrict__ pL, const float* __restrict__ pF,
    const float* __restrict__ pMg, const float* __restrict__ pLg,
    unsigned short* __restrict__ cc) {
  __shared__ float sc[QR][H_][NSPLIT];
  __shared__ float scg[QR][NSPLIT];
  int t = threadIdx.x;
  int i0 = blockIdx.x * QR;
  if (t < QR * H_) {
    int r = t >> 3, h = t & 7;
    size_t row = i0 + r;
    float ms[NSPLIT], ls[NSPLIT], m = -INFINITY;
#pragma unroll
    for (int s2 = 0; s2 < NSPLIT; ++s2) {
      ms[s2] = pM[((size_t)s2 * BN_ + row) * H_ + h];
      ls[s2] = pL[((size_t)s2 * BN_ + row) * H_ + h];
      m = fmaxf(m, ms[s2]);
    }
    float L = 0.f, e[NSPLIT];
#pragma unroll
    for (int s2 = 0; s2 < NSPLIT; ++s2) { e[s2] = __expf(ms[s2] - m); L += ls[s2] * e[s2]; }
    float invL = 1.0f / L;
#pragma unroll
    for (int s2 = 0; s2 < NSPLIT; ++s2) sc[r][h][s2] = e[s2] * invL;
  } else if (t < QR * H_ + QR) {
    int r = t - QR * H_;
    size_t row = i0 + r;
    float ms[NSPLIT], ls[NSPLIT], m = -INFINITY;
#pragma unroll
    for (int s2 = 0; s2 < NSPLIT; ++s2) {
      ms[s2] = pMg[(size_t)s2 * BN_ + row];
      ls[s2] = pLg[(size_t)s2 * BN_ + row];
      m = fmaxf(m, ms[s2]);
    }
    float L = 0.f, e[NSPLIT];
#pragma unroll
    for (int s2 = 0; s2 < NSPLIT; ++s2) { e[s2] = __expf(ms[s2] - m); L += ls[s2] * e[s2]; }
    float inv = 1.0f / (L * (float)N_);
#pragma unroll
    for (int s2 = 0; s2 < NSPLIT; ++s2) scg[r][s2] = e[s2] * inv;
  }
  __syncthreads();
  // coalesced: d fastest within each row
#pragma unroll
  for (int r = 0; r < QR; ++r) {
    size_t row = i0 + r;
    for (int d = t; d < D_; d += 256) {
      int h = d / HD_;
      float o = 0.f;
#pragma unroll
      for (int s2 = 0; s2 < NSPLIT; ++s2)
        o += b2f(pO[((size_t)s2 * BN_ + row) * D_ + d]) * sc[r][h][s2];
      cc[row * CCLD + d] = f2b(o);
    }
  }
  if (t < QR * 3) {
    int r = t / 3, c = t % 3;
    size_t row = i0 + r;
    float F = 0.f;
#pragma unroll
    for (int s2 = 0; s2 < NSPLIT; ++s2) F += pF[((size_t)s2 * BN_ + row) * 3 + c] * scg[r][s2];
    cc[row * CCLD + 384 + c] = f2b(F);
  }
  for (int idx = t; idx < QR * (CCLD - 387); idx += 256) {
    int r = idx / (CCLD - 387), col = 387 + idx % (CCLD - 387);
    cc[(size_t)(i0 + r) * CCLD + col] = 0;
  }
}

// ---------------------------------------------------------------- launch
extern "C" void kernel_launch(void* const* d_in, const int* in_sizes, int n_in,
                              void* d_out, int out_size, void* d_ws, size_t ws_size,
                              hipStream_t stream) {
  const float* x_rigid = (const float*)d_in[0];
  const float* ad      = (const float*)d_in[1];
  const float* ori     = (const float*)d_in[2];
  const float* dist    = (const float*)d_in[3];
  const int*   mask    = (const int*)d_in[4];
  const float* Wq  = (const float*)d_in[5];
  const float* bq  = (const float*)d_in[6];
  const float* Wk  = (const float*)d_in[7];
  const float* bk  = (const float*)d_in[8];
  const float* Wv  = (const float*)d_in[9];
  const float* bv  = (const float*)d_in[10];
  const float* W3  = (const float*)d_in[11];
  const float* b3  = (const float*)d_in[12];
  const float* Wmlp = (const float*)d_in[13];
  const float* bmlp = (const float*)d_in[14];
  const float* Wfc  = (const float*)d_in[15];
  const float* bfc  = (const float*)d_in[16];
  const float* Wff1 = (const float*)d_in[17];
  const float* bff1 = (const float*)d_in[18];
  const float* Wff2 = (const float*)d_in[19];
  const float* bff2 = (const float*)d_in[20];
  const float* ln1g = (const float*)d_in[21];
  const float* ln1b = (const float*)d_in[22];
  const float* ln2g = (const float*)d_in[23];
  const float* ln2b = (const float*)d_in[24];

  float* x = (float*)d_out;

  size_t off = 0;
  auto alloc = [&](size_t bytes) -> void* {
    void* r = (char*)d_ws + off;
    off = (off + bytes + 255) & ~(size_t)255;
    return r;
  };
  unsigned short* WqkvT = (unsigned short*)alloc((size_t)L_ * 1152 * D_ * 2);
  unsigned short* WfcT  = (unsigned short*)alloc((size_t)L_ * D_ * CCLD * 2);
  unsigned short* Wff1T = (unsigned short*)alloc((size_t)L_ * DFF2 * D_ * 2);
  unsigned short* Wff2T = (unsigned short*)alloc((size_t)L_ * D_ * DFF2 * 2);
  float* bqkv = (float*)alloc((size_t)L_ * 1152 * 4);
  unsigned short* qp  = (unsigned short*)alloc((size_t)BN_ * 512 * 2);
  unsigned short* kpf = (unsigned short*)alloc((size_t)2048 * 64 * 8 * 2);  // 2 MB frag-major K
  unsigned short* vf  = (unsigned short*)alloc((size_t)1536 * 64 * 8 * 2);  // 1.5 MB frag-major V
  unsigned short* hb  = (unsigned short*)alloc((size_t)BN_ * D_ * 2);
  unsigned short* h2  = (unsigned short*)alloc((size_t)BN_ * D_ * 2);
  unsigned short* cc  = (unsigned short*)alloc((size_t)BN_ * CCLD * 2);
  unsigned short* ffb = (unsigned short*)alloc((size_t)BN_ * DFF2 * 2);
  float* v3 = (float*)alloc((size_t)BN_ * 3 * 4);
  unsigned short* pO = (unsigned short*)alloc((size_t)NSPLIT * BN_ * D_ * 2);
  float* pM = (float*)alloc((size_t)NSPLIT * BN_ * H_ * 4);
  float* pL = (float*)alloc((size_t)NSPLIT * BN_ * H_ * 4);
  float* pF = (float*)alloc((size_t)NSPLIT * BN_ * 3 * 4);
  float* pMg = (float*)alloc((size_t)NSPLIT * BN_ * 4);
  float* pLg = (float*)alloc((size_t)NSPLIT * BN_ * 4);
  size_t need_base = off;
  // G (bf16, 12 B/pair): written by layer-0 attention, read by layers 1-3
  uint2* Ga = (uint2*)alloc(BNNc * 8);
  unsigned int* Gz = (unsigned int*)alloc(BNNc * 4);
  bool useG = (off <= ws_size);
  size_t off_g = useG ? off : need_base;
  off = off_g;
  unsigned short* db4 = (unsigned short*)alloc((size_t)L_ * BNNc * 2);
  bool use4 = (off <= ws_size);
  unsigned short* db1 = nullptr;
  if (!use4) {
    off = off_g;
    db1 = (unsigned short*)alloc(BNNc * 2);
    if (off > ws_size) return;  // insufficient scratch
  }
  if (ws_size < need_base) return;

  // one-time: unified weight pack + misc (copy/padzero/bias) + RBF-only precompute
  pack_all_kernel<<<dim3(984, 1, L_), 256, 0, stream>>>(Wq, Wk, Wv, Wfc, Wff1, Wff2,
                                                        WqkvT, WfcT, Wff1T, Wff2T);
  misc_kernel<<<5138, 256, 0, stream>>>(x, x_rigid, qp, kpf, bq, bk, bv, bqkv);
  if (use4) rbf4v_kernel<<<2048, 256, 0, stream>>>(dist, mask, Wmlp, bmlp, db4);

  for (int l = 0; l < L_; ++l) {
    const unsigned short* db_l = use4 ? (db4 + (size_t)l * BNNc) : db1;
    if (!use4) rbf_kernel<<<4096, 256, 0, stream>>>(dist, mask, Wmlp + l * 16, bmlp + l, db1);
    ln_kernel<true><<<BN_ / 4, 256, 0, stream>>>(x, ln1g + l * D_, ln1b + l * D_, hb,
                                                 W3 + (size_t)l * D_ * 3, b3 + l * 3, v3);
    mfma_gemm2<0><<<dim3(36, 32), 256, 0, stream>>>(
        hb, D_, WqkvT + (size_t)l * 1152 * D_, D_, bqkv + l * 1152,
        (float*)qp, (float*)kpf, (float*)vf, 0, D_);
    if (!useG)
      attn16_kernel<2><<<dim3(BN_ / 16, NSPLIT), 512, 0, stream>>>(
          qp, kpf, vf, db_l, Ga, Gz, ad, ori, v3, pO, pM, pL, pF, pMg, pLg);
    else if (l == 0)
      attn16_kernel<0><<<dim3(BN_ / 16, NSPLIT), 512, 0, stream>>>(
          qp, kpf, vf, db_l, Ga, Gz, ad, ori, v3, pO, pM, pL, pF, pMg, pLg);
    else
      attn16_kernel<1><<<dim3(BN_ / 16, NSPLIT), 512, 0, stream>>>(
          qp, kpf, vf, db_l, Ga, Gz, ad, ori, v3, pO, pM, pL, pF, pMg, pLg);
    combine_kernel<<<BN_ / QR, 256, 0, stream>>>(pO, pM, pL, pF, pMg, pLg, cc);
    mfma_gemm2<1><<<dim3(12, 32), 256, 0, stream>>>(
        cc, CCLD, WfcT + (size_t)l * D_ * CCLD, CCLD, bfc + l * D_, x, nullptr, nullptr, D_, CCLD);
    ln_kernel<false><<<BN_ / 4, 256, 0, stream>>>(x, ln2g + l * D_, ln2b + l * D_, h2,
                                                  nullptr, nullptr, nullptr);
    mfma_gemm2<2><<<dim3(16, 32), 256, 0, stream>>>(
        h2, D_, Wff1T + (size_t)l * DFF2 * D_, D_, bff1 + l * DFF2, (float*)ffb, nullptr, nullptr,
        DFF2, D_);
    mfma_gemm2<1><<<dim3(12, 32), 256, 0, stream>>>(
        ffb, DFF2, Wff2T + (size_t)l * D_ * DFF2, DFF2, bff2 + l * D_, x, nullptr, nullptr, D_,
        DFF2);
  }
}

// Round 16
// 316.337 us; speedup vs baseline: 1.0319x; 1.0319x over previous
//
#include <hip/hip_runtime.h>
#include <math.h>

constexpr int B_ = 2, N_ = 1024, D_ = 384, H_ = 8, HD_ = 48, DFF2 = 512, L_ = 4;
constexpr int BN_ = B_ * N_;                       // 2048 rows
constexpr size_t NNs = (size_t)N_ * N_;            // 1048576
constexpr size_t BNNc = (size_t)B_ * N_ * N_;      // 2097152
constexpr int JT = 64, NSPLIT = 4;
constexpr int CCLD = 448;                          // cc row stride (387 padded to 7*64)
constexpr float RSCALE = 0.14433756729740643f;     // 1/sqrt(48)

typedef short bf16x8 __attribute__((ext_vector_type(8)));
typedef float f32x4 __attribute__((ext_vector_type(4)));

__device__ inline float wsum(float v) {
#pragma unroll
  for (int m = 32; m; m >>= 1) v += __shfl_xor(v, m, 64);
  return v;
}
__device__ inline float b2f(unsigned int s) {
  union { unsigned int u; float f; } v; v.u = s << 16; return v.f;
}
__device__ inline unsigned short f2b(float f) {
  union { float f; unsigned int u; } v; v.f = f;
  unsigned int r = v.u + 0x7fffu + ((v.u >> 16) & 1u);
  return (unsigned short)(r >> 16);
}

// ---------------------------------------------------------------- misc: copy x + pad-zero qp/kpf + pack bias
__global__ __launch_bounds__(256) void misc_kernel(float* __restrict__ x,
                                                   const float* __restrict__ x_rigid,
                                                   unsigned short* __restrict__ qp,
                                                   unsigned short* __restrict__ kpf,
                                                   const float* __restrict__ bq,
                                                   const float* __restrict__ bk,
                                                   const float* __restrict__ bv,
                                                   float* __restrict__ bqkv) {
  int gid = blockIdx.x * 256 + threadIdx.x;
  if (gid < 786432) { x[gid] = x_rigid[gid]; return; }
  gid -= 786432;
  if (gid < 262144) {
    int r = gid >> 7, rem = gid & 127;
    int h = rem >> 4, c = rem & 15;
    qp[(size_t)r * 512 + h * 64 + 48 + c] = 0;
    return;
  }
  gid -= 262144;
  if (gid < 262144) {
    int fh = gid >> 8, rem = gid & 255;
    kpf[(size_t)fh * 1024 + 768 + rem] = 0;
    return;
  }
  gid -= 262144;
  if (gid < L_ * 1152) {
    int l = gid / 1152, n = gid % 1152;
    bqkv[gid] = (n < 384) ? bq[l * D_ + n] : (n < 768) ? bk[l * D_ + n - 384] : bv[l * D_ + n - 768];
  }
}

// ---------------------------------------------------------------- unified weight pack (all 6 transposes, 1 dispatch)
__global__ __launch_bounds__(256) void pack_all_kernel(
    const float* __restrict__ Wq, const float* __restrict__ Wk, const float* __restrict__ Wv,
    const float* __restrict__ Wfc, const float* __restrict__ Wff1, const float* __restrict__ Wff2,
    unsigned short* __restrict__ WqkvT, unsigned short* __restrict__ WfcT,
    unsigned short* __restrict__ Wff1T, unsigned short* __restrict__ Wff2T) {
  __shared__ float ts[32][33];
  const int bid = blockIdx.x;
  const int lz = blockIdx.z;
  const int t = threadIdx.x;
  const float* in;
  unsigned short* out;
  size_t istr, ostr;
  int K, Nc, Kpad, n0, k0;
  if (bid < 432) {  // Wq/Wk/Wv: 3 x (12x12)
    int which = bid / 144, r = bid % 144;
    n0 = (r % 12) * 32; k0 = (r / 12) * 32;
    in = (which == 0) ? Wq : (which == 1) ? Wk : Wv;
    istr = (size_t)D_ * D_;
    out = WqkvT + (size_t)which * 384 * 384;
    ostr = (size_t)1152 * D_;
    K = D_; Nc = D_; Kpad = D_;
  } else if (bid < 600) {  // Wfc: 12x14
    int r = bid - 432;
    n0 = (r % 12) * 32; k0 = (r / 12) * 32;
    in = Wfc; istr = (size_t)387 * D_;
    out = WfcT; ostr = (size_t)D_ * CCLD;
    K = 387; Nc = D_; Kpad = CCLD;
  } else if (bid < 792) {  // Wff1: 16x12
    int r = bid - 600;
    n0 = (r % 16) * 32; k0 = (r / 16) * 32;
    in = Wff1; istr = (size_t)D_ * DFF2;
    out = Wff1T; ostr = (size_t)DFF2 * D_;
    K = D_; Nc = DFF2; Kpad = D_;
  } else {  // Wff2: 12x16
    int r = bid - 792;
    n0 = (r % 12) * 32; k0 = (r / 12) * 32;
    in = Wff2; istr = (size_t)DFF2 * D_;
    out = Wff2T; ostr = (size_t)D_ * DFF2;
    K = DFF2; Nc = D_; Kpad = DFF2;
  }
  const float* inl = in + (size_t)lz * istr;
  unsigned short* outl = out + (size_t)lz * ostr;
#pragma unroll
  for (int u = 0; u < 4; ++u) {
    int i = t + u * 256, kk = i >> 5, nn = i & 31;
    int k = k0 + kk;
    ts[kk][nn] = (k < K) ? inl[(size_t)k * Nc + n0 + nn] : 0.f;
  }
  __syncthreads();
#pragma unroll
  for (int u = 0; u < 4; ++u) {
    int i = t + u * 256, nn = i >> 5, kk = i & 31;
    outl[(size_t)(n0 + nn) * Kpad + k0 + kk] = f2b(ts[kk][nn]);
  }
}

// ---------------------------------------------------------------- fused pair precompute: geometry + 4-layer RBF bias
// LDS-cached mlp weights; 1 pair/thread, 8192 blocks cover BNNc exactly.
__global__ __launch_bounds__(256) void precomp_kernel(const float* __restrict__ ori,
                                                      const float* __restrict__ ad,
                                                      const float* __restrict__ dist,
                                                      const int* __restrict__ mask,
                                                      const float* __restrict__ Wmlp,
                                                      const float* __restrict__ bmlp,
                                                      uint2* __restrict__ Ga,
                                                      unsigned int* __restrict__ Gz,
                                                      unsigned short* __restrict__ db4) {
  __shared__ float wm_s[64];
  __shared__ float bm_s[4];
  if (threadIdx.x < 64) wm_s[threadIdx.x] = Wmlp[threadIdx.x];
  if (threadIdx.x >= 64 && threadIdx.x < 68) bm_s[threadIdx.x - 64] = bmlp[threadIdx.x - 64];
  __syncthreads();
  size_t i = (size_t)blockIdx.x * 256 + threadIdx.x;
  if (i >= BNNc) return;
  {
    const float* op = ori + i * 9;
    const float* ap = ad + i * 3;
    float c0 = op[0] + op[3] + op[6];
    float c1 = op[1] + op[4] + op[7];
    float c2 = op[2] + op[5] + op[8];
    float a0 = ap[0], a1 = ap[1], a2 = ap[2];
    uint2 oa;
    oa.x = (unsigned int)f2b(a1 * c2) | ((unsigned int)f2b(a2 * c1) << 16);
    oa.y = (unsigned int)f2b(a2 * c0) | ((unsigned int)f2b(a0 * c2) << 16);
    Ga[i] = oa;
    Gz[i] = (unsigned int)f2b(a0 * c1) | ((unsigned int)f2b(a1 * c0) << 16);
  }
  {
    float dv = dist[i];
    bool msk = (mask[i] == 0);
    float rb[16];
#pragma unroll
    for (int r = 0; r < 16; ++r) {
      float tt = (dv - (float)r * (20.0f / 15.0f)) * 0.8f;
      rb[r] = __expf(-tt * tt);
    }
#pragma unroll
    for (int l2 = 0; l2 < L_; ++l2) {
      float sv = bm_s[l2];
#pragma unroll
      for (int r = 0; r < 16; ++r) sv += rb[r] * wm_s[l2 * 16 + r];
      db4[(size_t)l2 * BNNc + i] = f2b(msk ? -1e9f : sv);
    }
  }
}

// ---------------------------------------------------------------- fallback singles (small-workspace paths)
__global__ __launch_bounds__(256) void geomb_kernel(const float* __restrict__ ori,
                                                    const float* __restrict__ ad,
                                                    uint2* __restrict__ Ga,
                                                    unsigned int* __restrict__ Gz) {
  size_t i = (size_t)blockIdx.x * 256 + threadIdx.x;
  size_t stride = (size_t)gridDim.x * 256;
  for (; i < BNNc; i += stride) {
    const float* op = ori + i * 9;
    const float* ap = ad + i * 3;
    float c0 = op[0] + op[3] + op[6];
    float c1 = op[1] + op[4] + op[7];
    float c2 = op[2] + op[5] + op[8];
    float a0 = ap[0], a1 = ap[1], a2 = ap[2];
    uint2 oa;
    oa.x = (unsigned int)f2b(a1 * c2) | ((unsigned int)f2b(a2 * c1) << 16);
    oa.y = (unsigned int)f2b(a2 * c0) | ((unsigned int)f2b(a0 * c2) << 16);
    Ga[i] = oa;
    Gz[i] = (unsigned int)f2b(a0 * c1) | ((unsigned int)f2b(a1 * c0) << 16);
  }
}
__global__ __launch_bounds__(256) void rbf4_kernel(const float* __restrict__ dist,
                                                   const int* __restrict__ mask,
                                                   const float* __restrict__ Wmlp,
                                                   const float* __restrict__ bmlp,
                                                   unsigned short* __restrict__ db4) {
  size_t i = (size_t)blockIdx.x * 256 + threadIdx.x;
  size_t stride = (size_t)gridDim.x * 256;
  for (; i < BNNc; i += stride) {
    float dv = dist[i];
    bool msk = (mask[i] == 0);
    float rb[16];
#pragma unroll
    for (int r = 0; r < 16; ++r) {
      float tt = (dv - (float)r * (20.0f / 15.0f)) * 0.8f;
      rb[r] = __expf(-tt * tt);
    }
#pragma unroll
    for (int l2 = 0; l2 < L_; ++l2) {
      float sv = bmlp[l2];
#pragma unroll
      for (int r = 0; r < 16; ++r) sv += rb[r] * Wmlp[l2 * 16 + r];
      db4[(size_t)l2 * BNNc + i] = f2b(msk ? -1e9f : sv);
    }
  }
}
__global__ __launch_bounds__(256) void rbf_kernel(const float* __restrict__ dist,
                                                  const int* __restrict__ mask,
                                                  const float* __restrict__ wm,
                                                  const float* __restrict__ bm,
                                                  unsigned short* __restrict__ dbias) {
  size_t i = (size_t)blockIdx.x * 256 + threadIdx.x;
  size_t stride = (size_t)gridDim.x * 256;
  float w[16];
#pragma unroll
  for (int r = 0; r < 16; ++r) w[r] = wm[r];
  float b0 = bm[0];
  for (; i < BNNc; i += stride) {
    float dv = dist[i];
    float sv = b0;
#pragma unroll
    for (int r = 0; r < 16; ++r) {
      float tt = (dv - (float)r * (20.0f / 15.0f)) * 0.8f;
      sv += __expf(-tt * tt) * w[r];
    }
    dbias[i] = f2b((mask[i] == 0) ? -1e9f : sv);
  }
}

// ---------------------------------------------------------------- layernorm (wave per row, bf16 out), optional fused v3d
template <bool V3D>
__global__ __launch_bounds__(256) void ln_kernel(const float* __restrict__ x,
                                                 const float* __restrict__ g,
                                                 const float* __restrict__ b,
                                                 unsigned short* __restrict__ out,
                                                 const float* __restrict__ W3,
                                                 const float* __restrict__ b3,
                                                 float* __restrict__ v3d) {
  int lane = threadIdx.x & 63, wid = threadIdx.x >> 6;
  int row = blockIdx.x * 4 + wid;
  const float* xp = x + (size_t)row * D_;
  float v[6], s = 0.f, s2 = 0.f;
#pragma unroll
  for (int i = 0; i < 6; ++i) {
    v[i] = xp[lane + i * 64];
    s += v[i]; s2 += v[i] * v[i];
  }
  s = wsum(s); s2 = wsum(s2);
  float mean = s * (1.0f / D_);
  float var = s2 * (1.0f / D_) - mean * mean;
  float rstd = rsqrtf(var + 1e-5f);
  unsigned short* op = out + (size_t)row * D_;
  float a0 = 0.f, a1 = 0.f, a2 = 0.f;
#pragma unroll
  for (int i = 0; i < 6; ++i) {
    int d = lane + i * 64;
    float nv = (v[i] - mean) * rstd * g[d] + b[d];
    op[d] = f2b(nv);
    if (V3D) {
      a0 += nv * W3[d * 3 + 0];
      a1 += nv * W3[d * 3 + 1];
      a2 += nv * W3[d * 3 + 2];
    }
  }
  if (V3D) {
    a0 = wsum(a0); a1 = wsum(a1); a2 = wsum(a2);
    if (lane == 0) {
      v3d[row * 3 + 0] = a0 + b3[0];
      v3d[row * 3 + 1] = a1 + b3[1];
      v3d[row * 3 + 2] = a2 + b3[2];
    }
  }
}

// ---------------------------------------------------------------- bf16 MFMA GEMM v3: double-buffered LDS, 1 barrier/K-step
// Tile: BM=64 x BN=32 x BK=64. EPI 0: qkv (q dense, k/v frag-major); 1: fp32 += ; 2: relu->bf16.
template <int EPI>
__global__ __launch_bounds__(256) void mfma_gemm2(const unsigned short* __restrict__ A, int lda,
                                                  const unsigned short* __restrict__ WT, int ldw,
                                                  const float* __restrict__ bias,
                                                  float* __restrict__ C0, float* __restrict__ C1,
                                                  float* __restrict__ C2, int ldc, int K) {
  __shared__ __align__(16) unsigned short As[2][64 * 72];
  __shared__ __align__(16) unsigned short Bs[2][32 * 72];
  const int t = threadIdx.x;
  const int l = t & 63, w = t >> 6;
  const int lr = l & 15, lk = l >> 4;
  const int n0 = blockIdx.x * 32, m0 = blockIdx.y * 64;
  const int wm = (w & 1) * 32, wn = (w >> 1) * 16;
  const int arow = t >> 3, acol8 = (t & 7) * 8;
  uint4 ra0, ra1, rb;
  const unsigned short* pa0 = A + (size_t)(m0 + arow) * lda + acol8;
  const unsigned short* pa1 = A + (size_t)(m0 + arow + 32) * lda + acol8;
  const unsigned short* pb = WT + (size_t)(n0 + arow) * ldw + acol8;
  ra0 = *reinterpret_cast<const uint4*>(pa0);
  ra1 = *reinterpret_cast<const uint4*>(pa1);
  rb = *reinterpret_cast<const uint4*>(pb);
  f32x4 acc[2] = {};
  int p = 0;
  for (int kt = 0; kt < K; kt += 64) {
    *reinterpret_cast<uint4*>(&As[p][arow * 72 + acol8]) = ra0;
    *reinterpret_cast<uint4*>(&As[p][(arow + 32) * 72 + acol8]) = ra1;
    *reinterpret_cast<uint4*>(&Bs[p][arow * 72 + acol8]) = rb;
    if (kt + 64 < K) {
      ra0 = *reinterpret_cast<const uint4*>(pa0 + kt + 64);
      ra1 = *reinterpret_cast<const uint4*>(pa1 + kt + 64);
      rb = *reinterpret_cast<const uint4*>(pb + kt + 64);
    }
    __syncthreads();
#pragma unroll
    for (int ks = 0; ks < 2; ++ks) {
      bf16x8 av0 = *reinterpret_cast<const bf16x8*>(&As[p][(wm + lr) * 72 + ks * 32 + lk * 8]);
      bf16x8 av1 = *reinterpret_cast<const bf16x8*>(&As[p][(wm + 16 + lr) * 72 + ks * 32 + lk * 8]);
      bf16x8 bv = *reinterpret_cast<const bf16x8*>(&Bs[p][(wn + lr) * 72 + ks * 32 + lk * 8]);
      acc[0] = __builtin_amdgcn_mfma_f32_16x16x32_bf16(av0, bv, acc[0], 0, 0, 0);
      acc[1] = __builtin_amdgcn_mfma_f32_16x16x32_bf16(av1, bv, acc[1], 0, 0, 0);
    }
    p ^= 1;
  }
#pragma unroll
  for (int mi = 0; mi < 2; ++mi)
#pragma unroll
    for (int e = 0; e < 4; ++e) {
      int row = m0 + wm + mi * 16 + lk * 4 + e;
      int col = n0 + wn + lr;
      float v = acc[mi][e] + bias[col];
      if (EPI == 0) {
        if (col < 384) {
          int h = col / 48, hd = col - h * 48;
          ((unsigned short*)C0)[(size_t)row * 512 + h * 64 + hd] = f2b(v * RSCALE);
        } else if (col < 768) {
          int c2 = col - 384;
          int h = c2 / 48, d = c2 - h * 48;
          int b2 = row >> 10, j = row & 1023;
          int jb = j >> 4, jr = j & 15;
          int ks = d >> 5, dd = d & 31;
          size_t fid = (((size_t)(b2 * 64 + jb) * 8 + h) << 1) + ks;
          ((unsigned short*)C1)[fid * 512 + (size_t)(jr + ((dd >> 3) << 4)) * 8 + (d & 7)] = f2b(v);
        } else {
          int d = col - 768;
          int b2 = row >> 10, j = row & 1023;
          int jg = j >> 5, df = d >> 4;
          size_t fid = (size_t)(b2 * 32 + jg) * 24 + df;
          ((unsigned short*)C2)[fid * 512 + (size_t)((d & 15) + (((j & 31) >> 3) << 4)) * 8 + (j & 7)] = f2b(v);
        }
      }
      if (EPI == 1) C0[(size_t)row * ldc + col] += v;
      if (EPI == 2) ((unsigned short*)C0)[(size_t)row * ldc + col] = f2b(fmaxf(v, 0.f));
    }
}

// ---------------------------------------------------------------- MFMA fused attention v8: 512 threads, head-per-wave,
// frag-major K/V, 2 barriers/tile, defer-max THR=8, tile-top prefetch of frame geometry (G, v3d).
template <bool USEG>
__global__ __launch_bounds__(512, 4) void attn16_kernel(
    const unsigned short* __restrict__ qp, const unsigned short* __restrict__ kpf,
    const unsigned short* __restrict__ vf, const unsigned short* __restrict__ db_l,
    const uint2* __restrict__ Ga, const unsigned int* __restrict__ Gz,
    const float* __restrict__ ad, const float* __restrict__ ori,
    const float* __restrict__ v3d,
    unsigned short* __restrict__ pO, float* __restrict__ pM, float* __restrict__ pL,
    float* __restrict__ pF, float* __restrict__ pMg, float* __restrict__ pLg) {
  __shared__ __align__(16) unsigned short pbuf[8 * 16 * 72];  // P bf16 [h][r][72] (wave-local rows)
  __shared__ __align__(16) unsigned short msw[8 * 16 * 68];   // per-head partials bf16; plane 0 reused for merged probs
  __shared__ __align__(16) float dbs[16 * 68];                // dbias tile (f32 after convert)
  __shared__ float fg_s[16];

  const int t = threadIdx.x;
  const int wv = t >> 6, l = t & 63;  // wv = head
  const int lr = l & 15, lk = l >> 4;
  const int sgrp = blockIdx.y;
  const int i0 = blockIdx.x * 16;
  const int b = i0 >> 10, ib = i0 & 1023;
  const int mr = t >> 5, mc = t & 31;  // merged softmax role: 32 threads per row

  const bf16x8 qf0 = *reinterpret_cast<const bf16x8*>(
      qp + (size_t)(i0 + lr) * 512 + wv * 64 + lk * 8);
  const bf16x8 qf1 = *reinterpret_cast<const bf16x8*>(
      qp + (size_t)(i0 + lr) * 512 + wv * 64 + 32 + lk * 8);

  f32x4 Ofr[3] = {};
  float fracc[2][3] = {};
  float m_ph[4], l_ph[4], fhv[4];
#pragma unroll
  for (int e = 0; e < 4; ++e) { m_ph[e] = -INFINITY; l_ph[e] = 0.f; }
  float m_mg = -INFINITY, l_mg = 0.f;

  for (int jt = sgrp * (N_ / NSPLIT); jt < (sgrp + 1) * (N_ / NSPLIT); jt += JT) {
    // ---- tile-top prefetch: frame geometry for THIS tile (consumed at the frame step) ----
    uint2 ga_r0, ga_r1;
    unsigned int gz_r0, gz_r1;
    float w0p = 0.f, w1p = 0.f, w2p = 0.f;
    if (USEG) {
      const float* vp = v3d + (size_t)((b << 10) + jt + l) * 3;
      w0p = vp[0]; w1p = vp[1]; w2p = vp[2];
      size_t pij0 = ((size_t)b * N_ + (ib + wv * 2)) * N_ + jt + l;
      ga_r0 = Ga[pij0];
      gz_r0 = Gz[pij0];
      ga_r1 = Ga[pij0 + N_];
      gz_r1 = Gz[pij0 + N_];
    }
    // ---- Phase 1: stage dbias (bf16 -> f32), QK^T MFMA (coalesced frag loads) ----
    if (t < 128) {
      int r = t >> 3, c4 = t & 7;
      const uint4* src = reinterpret_cast<const uint4*>(
                             db_l + (size_t)b * NNs + (size_t)(ib + r) * N_ + jt) + c4;
      uint4 v = *src;
      float* dp = &dbs[r * 68 + c4 * 8];
      dp[0] = b2f(v.x & 0xffffu); dp[1] = b2f(v.x >> 16);
      dp[2] = b2f(v.y & 0xffffu); dp[3] = b2f(v.y >> 16);
      dp[4] = b2f(v.z & 0xffffu); dp[5] = b2f(v.z >> 16);
      dp[6] = b2f(v.w & 0xffffu); dp[7] = b2f(v.w >> 16);
    }
    f32x4 sc[4];
    {
      const unsigned short* kbase =
          kpf + ((((size_t)(b * 64) + (jt >> 4)) * 8 + wv) * 2 * 64 + l) * 8;
      bf16x8 kf0[4], kf1[4];
#pragma unroll
      for (int nj = 0; nj < 4; ++nj) {
        kf0[nj] = *reinterpret_cast<const bf16x8*>(kbase + (size_t)nj * 16 * 512);
        kf1[nj] = *reinterpret_cast<const bf16x8*>(kbase + (size_t)nj * 16 * 512 + 512);
      }
#pragma unroll
      for (int nj = 0; nj < 4; ++nj) {
        f32x4 acc = {};
        acc = __builtin_amdgcn_mfma_f32_16x16x32_bf16(qf0, kf0[nj], acc, 0, 0, 0);
        acc = __builtin_amdgcn_mfma_f32_16x16x32_bf16(qf1, kf1[nj], acc, 0, 0, 0);
        sc[nj] = acc;
      }
    }
#pragma unroll
    for (int nj = 0; nj < 4; ++nj)
#pragma unroll
      for (int e = 0; e < 4; ++e)
        msw[(wv * 16 + lk * 4 + e) * 68 + nj * 16 + lr] = f2b(sc[nj][e]);
    __syncthreads();
    // ---- Phase 2a: per-head softmax in registers, defer-max THR=8 ----
    bool needO;
    {
      float sv[4][4];
#pragma unroll
      for (int nj = 0; nj < 4; ++nj)
#pragma unroll
        for (int e = 0; e < 4; ++e)
          sv[nj][e] = sc[nj][e] + dbs[(lk * 4 + e) * 68 + nj * 16 + lr];
      float lm[4];
      bool need = false;
#pragma unroll
      for (int e = 0; e < 4; ++e) {
        lm[e] = fmaxf(fmaxf(sv[0][e], sv[1][e]), fmaxf(sv[2][e], sv[3][e]));
        need = need || (lm[e] > m_ph[e] + 8.f);
      }
      needO = __any(need);
      if (needO) {
#pragma unroll
        for (int e = 0; e < 4; ++e) {
          float rm = lm[e];
          rm = fmaxf(rm, __shfl_xor(rm, 1, 64));
          rm = fmaxf(rm, __shfl_xor(rm, 2, 64));
          rm = fmaxf(rm, __shfl_xor(rm, 4, 64));
          rm = fmaxf(rm, __shfl_xor(rm, 8, 64));
          float nm = fmaxf(m_ph[e], rm);
          fhv[e] = __expf(m_ph[e] - nm);
          m_ph[e] = nm;
          l_ph[e] *= fhv[e];
        }
      }
#pragma unroll
      for (int e = 0; e < 4; ++e) {
        float ls = 0.f;
#pragma unroll
        for (int nj = 0; nj < 4; ++nj) {
          float pv = __expf(sv[nj][e] - m_ph[e]);
          sv[nj][e] = pv;
          ls += pv;
        }
        ls += __shfl_xor(ls, 1, 64);
        ls += __shfl_xor(ls, 2, 64);
        ls += __shfl_xor(ls, 4, 64);
        ls += __shfl_xor(ls, 8, 64);
        l_ph[e] += ls;
#pragma unroll
        for (int nj = 0; nj < 4; ++nj)
          pbuf[(wv * 16 + lk * 4 + e) * 72 + nj * 16 + lr] = f2b(sv[nj][e]);
      }
    }
    // ---- Phase 2b: merged softmax (sum 8 bf16 planes + 8*dbias), defer-max ----
    {
      float mv[2];
#pragma unroll
      for (int i = 0; i < 2; ++i) {
        int j = mc + 32 * i;
        float s = 8.f * dbs[mr * 68 + j];
#pragma unroll
        for (int h = 0; h < 8; ++h) s += b2f(msw[(h * 16 + mr) * 68 + j]);
        mv[i] = s;
      }
      float lm2 = fmaxf(mv[0], mv[1]);
      bool needm = __any(lm2 > m_mg + 8.f);
      if (needm) {
        float tmax = lm2;
        tmax = fmaxf(tmax, __shfl_xor(tmax, 1, 64));
        tmax = fmaxf(tmax, __shfl_xor(tmax, 2, 64));
        tmax = fmaxf(tmax, __shfl_xor(tmax, 4, 64));
        tmax = fmaxf(tmax, __shfl_xor(tmax, 8, 64));
        tmax = fmaxf(tmax, __shfl_xor(tmax, 16, 64));
        float nm = fmaxf(m_mg, tmax);
        float f = __expf(m_mg - nm);
        m_mg = nm;
        l_mg *= f;
        if (mc == 0) fg_s[mr] = f;
      } else if (mc == 0) {
        fg_s[mr] = 1.f;
      }
      float lsum = 0.f;
#pragma unroll
      for (int i = 0; i < 2; ++i) {
        mv[i] = __expf(mv[i] - m_mg);
        lsum += mv[i];
        msw[mr * 68 + mc + 32 * i] = f2b(mv[i]);
      }
      lsum += __shfl_xor(lsum, 1, 64);
      lsum += __shfl_xor(lsum, 2, 64);
      lsum += __shfl_xor(lsum, 4, 64);
      lsum += __shfl_xor(lsum, 8, 64);
      lsum += __shfl_xor(lsum, 16, 64);
      l_mg += lsum;
    }
    // ---- Phase 3 (no barrier needed: all reads wave-local): PV MFMA + frame ----
    {
      bf16x8 af0 = *reinterpret_cast<const bf16x8*>(&pbuf[(wv * 16 + lr) * 72 + lk * 8]);
      bf16x8 af1 = *reinterpret_cast<const bf16x8*>(&pbuf[(wv * 16 + lr) * 72 + 32 + lk * 8]);
      const unsigned short* vbase =
          vf + ((((size_t)(b * 32) + (jt >> 5)) * 24 + wv * 3) * 64 + l) * 8;
#pragma unroll
      for (int ni = 0; ni < 3; ++ni) {
        bf16x8 bf0 = *reinterpret_cast<const bf16x8*>(vbase + (size_t)ni * 512);
        bf16x8 bf1 = *reinterpret_cast<const bf16x8*>(vbase + (size_t)(24 + ni) * 512);
        f32x4 o = Ofr[ni];
        if (needO) {
#pragma unroll
          for (int e = 0; e < 4; ++e) o[e] *= fhv[e];
        }
        o = __builtin_amdgcn_mfma_f32_16x16x32_bf16(af0, bf0, o, 0, 0, 0);
        o = __builtin_amdgcn_mfma_f32_16x16x32_bf16(af1, bf1, o, 0, 0, 0);
        Ofr[ni] = o;
      }
    }
    {
      float w0, w1, w2;
      if (USEG) {
        w0 = w0p; w1 = w1p; w2 = w2p;
      } else {
        const float* vp = v3d + (size_t)((b << 10) + jt + l) * 3;
        w0 = vp[0]; w1 = vp[1]; w2 = vp[2];
      }
#pragma unroll
      for (int e = 0; e < 2; ++e) {
        int r = wv * 2 + e;
        float pm = b2f(msw[r * 68 + l]);
        float d0, d1, d2;
        if (USEG) {
          uint2 ga = (e == 0) ? ga_r0 : ga_r1;
          unsigned int gz = (e == 0) ? gz_r0 : gz_r1;
          float g0 = b2f(ga.x & 0xffffu), g1 = b2f(ga.x >> 16);
          float g2 = b2f(ga.y & 0xffffu), g3 = b2f(ga.y >> 16);
          float g4 = b2f(gz & 0xffffu), g5 = b2f(gz >> 16);
          d0 = g0 * w2 - g1 * w1;
          d1 = g2 * w0 - g3 * w2;
          d2 = g4 * w1 - g5 * w0;
        } else {
          size_t pij = ((size_t)b * N_ + (ib + r)) * N_ + jt + l;
          const float* op = ori + pij * 9;
          const float* ap = ad + pij * 3;
          float a0 = ap[0], a1 = ap[1], a2 = ap[2];
          float u0 = (op[0] + op[3] + op[6]) * w0;
          float u1 = (op[1] + op[4] + op[7]) * w1;
          float u2 = (op[2] + op[5] + op[8]) * w2;
          d0 = a1 * u2 - a2 * u1; d1 = a2 * u0 - a0 * u2; d2 = a0 * u1 - a1 * u0;
        }
        float fgr = fg_s[r];
        fracc[e][0] = fracc[e][0] * fgr + pm * d0;
        fracc[e][1] = fracc[e][1] * fgr + pm * d1;
        fracc[e][2] = fracc[e][2] * fgr + pm * d2;
      }
    }
    __syncthreads();
  }
  // ---- epilogue: write split partials (O in bf16) ----
  const size_t rowb = (size_t)sgrp * BN_ + i0;
#pragma unroll
  for (int ni = 0; ni < 3; ++ni)
#pragma unroll
    for (int e = 0; e < 4; ++e)
      pO[(rowb + lk * 4 + e) * D_ + wv * 48 + ni * 16 + lr] = f2b(Ofr[ni][e]);
#pragma unroll
  for (int e = 0; e < 2; ++e)
#pragma unroll
    for (int c = 0; c < 3; ++c) {
      float v = wsum(fracc[e][c]);
      if (l == 0) pF[(rowb + wv * 2 + e) * 3 + c] = v;
    }
  if (lr == 0) {
#pragma unroll
    for (int e = 0; e < 4; ++e) {
      pM[(rowb + lk * 4 + e) * H_ + wv] = m_ph[e];
      pL[(rowb + lk * 4 + e) * H_ + wv] = l_ph[e];
    }
  }
  if (mc == 0) { pMg[rowb + mr] = m_mg; pLg[rowb + mr] = l_mg; }
}

// ---------------------------------------------------------------- combine split partials -> cc (bf16, padded)
constexpr int QR = 8;
__global__ __launch_bounds__(256) void combine_kernel(
    const unsigned short* __restrict__ pO, const float* __restrict__ pM,
    const float* __restrict__ pL, const float* __restrict__ pF,
    const float* __restrict__ pMg, const float* __restrict__ pLg,
    unsigned short* __restrict__ cc) {
  __shared__ float sc[QR][H_][NSPLIT];
  __shared__ float scg[QR][NSPLIT];
  int t = threadIdx.x;
  int i0 = blockIdx.x * QR;
  if (t < QR * H_) {
    int r = t >> 3, h = t & 7;
    size_t row = i0 + r;
    float ms[NSPLIT], ls[NSPLIT], m = -INFINITY;
#pragma unroll
    for (int s2 = 0; s2 < NSPLIT; ++s2) {
      ms[s2] = pM[((size_t)s2 * BN_ + row) * H_ + h];
      ls[s2] = pL[((size_t)s2 * BN_ + row) * H_ + h];
      m = fmaxf(m, ms[s2]);
    }
    float L = 0.f, e[NSPLIT];
#pragma unroll
    for (int s2 = 0; s2 < NSPLIT; ++s2) { e[s2] = __expf(ms[s2] - m); L += ls[s2] * e[s2]; }
    float invL = 1.0f / L;
#pragma unroll
    for (int s2 = 0; s2 < NSPLIT; ++s2) sc[r][h][s2] = e[s2] * invL;
  } else if (t < QR * H_ + QR) {
    int r = t - QR * H_;
    size_t row = i0 + r;
    float ms[NSPLIT], ls[NSPLIT], m = -INFINITY;
#pragma unroll
    for (int s2 = 0; s2 < NSPLIT; ++s2) {
      ms[s2] = pMg[(size_t)s2 * BN_ + row];
      ls[s2] = pLg[(size_t)s2 * BN_ + row];
      m = fmaxf(m, ms[s2]);
    }
    float L = 0.f, e[NSPLIT];
#pragma unroll
    for (int s2 = 0; s2 < NSPLIT; ++s2) { e[s2] = __expf(ms[s2] - m); L += ls[s2] * e[s2]; }
    float inv = 1.0f / (L * (float)N_);
#pragma unroll
    for (int s2 = 0; s2 < NSPLIT; ++s2) scg[r][s2] = e[s2] * inv;
  }
  __syncthreads();
  // coalesced: d fastest within each row
#pragma unroll
  for (int r = 0; r < QR; ++r) {
    size_t row = i0 + r;
    for (int d = t; d < D_; d += 256) {
      int h = d / HD_;
      float o = 0.f;
#pragma unroll
      for (int s2 = 0; s2 < NSPLIT; ++s2)
        o += b2f(pO[((size_t)s2 * BN_ + row) * D_ + d]) * sc[r][h][s2];
      cc[row * CCLD + d] = f2b(o);
    }
  }
  if (t < QR * 3) {
    int r = t / 3, c = t % 3;
    size_t row = i0 + r;
    float F = 0.f;
#pragma unroll
    for (int s2 = 0; s2 < NSPLIT; ++s2) F += pF[((size_t)s2 * BN_ + row) * 3 + c] * scg[r][s2];
    cc[row * CCLD + 384 + c] = f2b(F);
  }
  for (int idx = t; idx < QR * (CCLD - 387); idx += 256) {
    int r = idx / (CCLD - 387), col = 387 + idx % (CCLD - 387);
    cc[(size_t)(i0 + r) * CCLD + col] = 0;
  }
}

// ---------------------------------------------------------------- launch
extern "C" void kernel_launch(void* const* d_in, const int* in_sizes, int n_in,
                              void* d_out, int out_size, void* d_ws, size_t ws_size,
                              hipStream_t stream) {
  const float* x_rigid = (const float*)d_in[0];
  const float* ad      = (const float*)d_in[1];
  const float* ori     = (const float*)d_in[2];
  const float* dist    = (const float*)d_in[3];
  const int*   mask    = (const int*)d_in[4];
  const float* Wq  = (const float*)d_in[5];
  const float* bq  = (const float*)d_in[6];
  const float* Wk  = (const float*)d_in[7];
  const float* bk  = (const float*)d_in[8];
  const float* Wv  = (const float*)d_in[9];
  const float* bv  = (const float*)d_in[10];
  const float* W3  = (const float*)d_in[11];
  const float* b3  = (const float*)d_in[12];
  const float* Wmlp = (const float*)d_in[13];
  const float* bmlp = (const float*)d_in[14];
  const float* Wfc  = (const float*)d_in[15];
  const float* bfc  = (const float*)d_in[16];
  const float* Wff1 = (const float*)d_in[17];
  const float* bff1 = (const float*)d_in[18];
  const float* Wff2 = (const float*)d_in[19];
  const float* bff2 = (const float*)d_in[20];
  const float* ln1g = (const float*)d_in[21];
  const float* ln1b = (const float*)d_in[22];
  const float* ln2g = (const float*)d_in[23];
  const float* ln2b = (const float*)d_in[24];

  float* x = (float*)d_out;

  size_t off = 0;
  auto alloc = [&](size_t bytes) -> void* {
    void* r = (char*)d_ws + off;
    off = (off + bytes + 255) & ~(size_t)255;
    return r;
  };
  unsigned short* WqkvT = (unsigned short*)alloc((size_t)L_ * 1152 * D_ * 2);
  unsigned short* WfcT  = (unsigned short*)alloc((size_t)L_ * D_ * CCLD * 2);
  unsigned short* Wff1T = (unsigned short*)alloc((size_t)L_ * DFF2 * D_ * 2);
  unsigned short* Wff2T = (unsigned short*)alloc((size_t)L_ * D_ * DFF2 * 2);
  float* bqkv = (float*)alloc((size_t)L_ * 1152 * 4);
  unsigned short* qp  = (unsigned short*)alloc((size_t)BN_ * 512 * 2);
  unsigned short* kpf = (unsigned short*)alloc((size_t)2048 * 64 * 8 * 2);  // 2 MB frag-major K
  unsigned short* vf  = (unsigned short*)alloc((size_t)1536 * 64 * 8 * 2);  // 1.5 MB frag-major V
  unsigned short* hb  = (unsigned short*)alloc((size_t)BN_ * D_ * 2);
  unsigned short* h2  = (unsigned short*)alloc((size_t)BN_ * D_ * 2);
  unsigned short* cc  = (unsigned short*)alloc((size_t)BN_ * CCLD * 2);
  unsigned short* ffb = (unsigned short*)alloc((size_t)BN_ * DFF2 * 2);
  float* v3 = (float*)alloc((size_t)BN_ * 3 * 4);
  unsigned short* pO = (unsigned short*)alloc((size_t)NSPLIT * BN_ * D_ * 2);
  float* pM = (float*)alloc((size_t)NSPLIT * BN_ * H_ * 4);
  float* pL = (float*)alloc((size_t)NSPLIT * BN_ * H_ * 4);
  float* pF = (float*)alloc((size_t)NSPLIT * BN_ * 3 * 4);
  float* pMg = (float*)alloc((size_t)NSPLIT * BN_ * 4);
  float* pLg = (float*)alloc((size_t)NSPLIT * BN_ * 4);
  size_t need_base = off;
  // G (bf16, 12 B/pair) has priority over db4 (bigger per-layer savings)
  uint2* Ga = (uint2*)alloc(BNNc * 8);
  unsigned int* Gz = (unsigned int*)alloc(BNNc * 4);
  bool useG = (off <= ws_size);
  size_t off_g = useG ? off : need_base;
  off = off_g;
  unsigned short* db4 = (unsigned short*)alloc((size_t)L_ * BNNc * 2);
  bool use4 = (off <= ws_size);
  unsigned short* db1 = nullptr;
  if (!use4) {
    off = off_g;
    db1 = (unsigned short*)alloc(BNNc * 2);
    if (off > ws_size) return;  // insufficient scratch
  }
  if (ws_size < need_base) return;

  // one-time: unified weight pack (6 transposes in 1 dispatch) + misc (copy/padzero/bias)
  pack_all_kernel<<<dim3(984, 1, L_), 256, 0, stream>>>(Wq, Wk, Wv, Wfc, Wff1, Wff2,
                                                        WqkvT, WfcT, Wff1T, Wff2T);
  misc_kernel<<<5138, 256, 0, stream>>>(x, x_rigid, qp, kpf, bq, bk, bv, bqkv);
  if (useG && use4) {
    precomp_kernel<<<8192, 256, 0, stream>>>(ori, ad, dist, mask, Wmlp, bmlp, Ga, Gz, db4);
  } else {
    if (useG) geomb_kernel<<<4096, 256, 0, stream>>>(ori, ad, Ga, Gz);
    if (use4) rbf4_kernel<<<4096, 256, 0, stream>>>(dist, mask, Wmlp, bmlp, db4);
  }

  for (int l = 0; l < L_; ++l) {
    const unsigned short* db_l = use4 ? (db4 + (size_t)l * BNNc) : db1;
    if (!use4) rbf_kernel<<<4096, 256, 0, stream>>>(dist, mask, Wmlp + l * 16, bmlp + l, db1);
    ln_kernel<true><<<BN_ / 4, 256, 0, stream>>>(x, ln1g + l * D_, ln1b + l * D_, hb,
                                                 W3 + (size_t)l * D_ * 3, b3 + l * 3, v3);
    mfma_gemm2<0><<<dim3(36, 32), 256, 0, stream>>>(
        hb, D_, WqkvT + (size_t)l * 1152 * D_, D_, bqkv + l * 1152,
        (float*)qp, (float*)kpf, (float*)vf, 0, D_);
    if (useG)
      attn16_kernel<true><<<dim3(BN_ / 16, NSPLIT), 512, 0, stream>>>(
          qp, kpf, vf, db_l, Ga, Gz, ad, ori, v3, pO, pM, pL, pF, pMg, pLg);
    else
      attn16_kernel<false><<<dim3(BN_ / 16, NSPLIT), 512, 0, stream>>>(
          qp, kpf, vf, db_l, Ga, Gz, ad, ori, v3, pO, pM, pL, pF, pMg, pLg);
    combine_kernel<<<BN_ / QR, 256, 0, stream>>>(pO, pM, pL, pF, pMg, pLg, cc);
    mfma_gemm2<1><<<dim3(12, 32), 256, 0, stream>>>(
        cc, CCLD, WfcT + (size_t)l * D_ * CCLD, CCLD, bfc + l * D_, x, nullptr, nullptr, D_, CCLD);
    ln_kernel<false><<<BN_ / 4, 256, 0, stream>>>(x, ln2g + l * D_, ln2b + l * D_, h2,
                                                  nullptr, nullptr, nullptr);
    mfma_gemm2<2><<<dim3(16, 32), 256, 0, stream>>>(
        h2, D_, Wff1T + (size_t)l * DFF2 * D_, D_, bff1 + l * DFF2, (float*)ffb, nullptr, nullptr,
        DFF2, D_);
    mfma_gemm2<1><<<dim3(12, 32), 256, 0, stream>>>(
        ffb, DFF2, Wff2T + (size_t)l * D_ * DFF2, DFF2, bff2 + l * D_, x, nullptr, nullptr, D_,
        DFF2);
  }
}

// Round 17
// 315.542 us; speedup vs baseline: 1.0345x; 1.0025x over previous
//
#include <hip/hip_runtime.h>
#include <math.h>

constexpr int B_ = 2, N_ = 1024, D_ = 384, H_ = 8, HD_ = 48, DFF2 = 512, L_ = 4;
constexpr int BN_ = B_ * N_;                       // 2048 rows
constexpr size_t NNs = (size_t)N_ * N_;            // 1048576
constexpr size_t BNNc = (size_t)B_ * N_ * N_;      // 2097152
constexpr int JT = 64, NSPLIT = 4;
constexpr int CCLD = 448;                          // cc row stride (387 padded to 7*64)
constexpr float RSCALE = 0.14433756729740643f;     // 1/sqrt(48)

typedef short bf16x8 __attribute__((ext_vector_type(8)));
typedef float f32x4 __attribute__((ext_vector_type(4)));

__device__ inline float wsum(float v) {
#pragma unroll
  for (int m = 32; m; m >>= 1) v += __shfl_xor(v, m, 64);
  return v;
}
__device__ inline float b2f(unsigned int s) {
  union { unsigned int u; float f; } v; v.u = s << 16; return v.f;
}
__device__ inline unsigned short f2b(float f) {
  union { float f; unsigned int u; } v; v.f = f;
  unsigned int r = v.u + 0x7fffu + ((v.u >> 16) & 1u);
  return (unsigned short)(r >> 16);
}

// ---------------------------------------------------------------- misc: copy x + pad-zero qp/kpf + pack bias
__global__ __launch_bounds__(256) void misc_kernel(float* __restrict__ x,
                                                   const float* __restrict__ x_rigid,
                                                   unsigned short* __restrict__ qp,
                                                   unsigned short* __restrict__ kpf,
                                                   const float* __restrict__ bq,
                                                   const float* __restrict__ bk,
                                                   const float* __restrict__ bv,
                                                   float* __restrict__ bqkv) {
  int gid = blockIdx.x * 256 + threadIdx.x;
  if (gid < 786432) { x[gid] = x_rigid[gid]; return; }
  gid -= 786432;
  if (gid < 262144) {
    int r = gid >> 7, rem = gid & 127;
    int h = rem >> 4, c = rem & 15;
    qp[(size_t)r * 512 + h * 64 + 48 + c] = 0;
    return;
  }
  gid -= 262144;
  if (gid < 262144) {
    int fh = gid >> 8, rem = gid & 255;
    kpf[(size_t)fh * 1024 + 768 + rem] = 0;
    return;
  }
  gid -= 262144;
  if (gid < L_ * 1152) {
    int l = gid / 1152, n = gid % 1152;
    bqkv[gid] = (n < 384) ? bq[l * D_ + n] : (n < 768) ? bk[l * D_ + n - 384] : bv[l * D_ + n - 768];
  }
}

// ---------------------------------------------------------------- unified weight pack (all 6 transposes, 1 dispatch)
__global__ __launch_bounds__(256) void pack_all_kernel(
    const float* __restrict__ Wq, const float* __restrict__ Wk, const float* __restrict__ Wv,
    const float* __restrict__ Wfc, const float* __restrict__ Wff1, const float* __restrict__ Wff2,
    unsigned short* __restrict__ WqkvT, unsigned short* __restrict__ WfcT,
    unsigned short* __restrict__ Wff1T, unsigned short* __restrict__ Wff2T) {
  __shared__ float ts[32][33];
  const int bid = blockIdx.x;
  const int lz = blockIdx.z;
  const int t = threadIdx.x;
  const float* in;
  unsigned short* out;
  size_t istr, ostr;
  int K, Nc, Kpad, n0, k0;
  if (bid < 432) {  // Wq/Wk/Wv: 3 x (12x12)
    int which = bid / 144, r = bid % 144;
    n0 = (r % 12) * 32; k0 = (r / 12) * 32;
    in = (which == 0) ? Wq : (which == 1) ? Wk : Wv;
    istr = (size_t)D_ * D_;
    out = WqkvT + (size_t)which * 384 * 384;
    ostr = (size_t)1152 * D_;
    K = D_; Nc = D_; Kpad = D_;
  } else if (bid < 600) {  // Wfc: 12x14
    int r = bid - 432;
    n0 = (r % 12) * 32; k0 = (r / 12) * 32;
    in = Wfc; istr = (size_t)387 * D_;
    out = WfcT; ostr = (size_t)D_ * CCLD;
    K = 387; Nc = D_; Kpad = CCLD;
  } else if (bid < 792) {  // Wff1: 16x12
    int r = bid - 600;
    n0 = (r % 16) * 32; k0 = (r / 16) * 32;
    in = Wff1; istr = (size_t)D_ * DFF2;
    out = Wff1T; ostr = (size_t)DFF2 * D_;
    K = D_; Nc = DFF2; Kpad = D_;
  } else {  // Wff2: 12x16
    int r = bid - 792;
    n0 = (r % 12) * 32; k0 = (r / 12) * 32;
    in = Wff2; istr = (size_t)DFF2 * D_;
    out = Wff2T; ostr = (size_t)D_ * DFF2;
    K = DFF2; Nc = D_; Kpad = DFF2;
  }
  const float* inl = in + (size_t)lz * istr;
  unsigned short* outl = out + (size_t)lz * ostr;
#pragma unroll
  for (int u = 0; u < 4; ++u) {
    int i = t + u * 256, kk = i >> 5, nn = i & 31;
    int k = k0 + kk;
    ts[kk][nn] = (k < K) ? inl[(size_t)k * Nc + n0 + nn] : 0.f;
  }
  __syncthreads();
#pragma unroll
  for (int u = 0; u < 4; ++u) {
    int i = t + u * 256, nn = i >> 5, kk = i & 31;
    outl[(size_t)(n0 + nn) * Kpad + k0 + kk] = f2b(ts[kk][nn]);
  }
}

// ---------------------------------------------------------------- fused pair precompute v3: linear-coalesced + LDS redistribute
// Block = 256 pairs. ori/ad read as flat arrays (unit lane stride -> minimal memory requests),
// staged in LDS, then per-thread gathers its 9/3 values (stride-9/3 word reads, <=2-way conflicts).
__global__ __launch_bounds__(256) void precomp_kernel(const float* __restrict__ ori,
                                                      const float* __restrict__ ad,
                                                      const float* __restrict__ dist,
                                                      const int* __restrict__ mask,
                                                      const float* __restrict__ Wmlp,
                                                      const float* __restrict__ bmlp,
                                                      uint2* __restrict__ Ga,
                                                      unsigned int* __restrict__ Gz,
                                                      unsigned short* __restrict__ db4) {
  __shared__ float oris[2304];
  __shared__ float ads[768];
  __shared__ float wm_s[64];
  __shared__ float bm_s[4];
  const int t = threadIdx.x;
  if (t < 64) wm_s[t] = Wmlp[t];
  if (t >= 64 && t < 68) bm_s[t - 64] = bmlp[t - 64];
  const size_t base = (size_t)blockIdx.x * 256;  // 8192 blocks cover BNNc exactly
  const float* orib = ori + base * 9;
#pragma unroll
  for (int u = 0; u < 9; ++u) oris[t + u * 256] = orib[t + u * 256];
  const float* adb = ad + base * 3;
#pragma unroll
  for (int u = 0; u < 3; ++u) ads[t + u * 256] = adb[t + u * 256];
  float dv = dist[base + t];
  int mk = mask[base + t];
  __syncthreads();
  const size_t i = base + t;
  {
    const float* op = &oris[t * 9];
    const float* ap = &ads[t * 3];
    float c0 = op[0] + op[3] + op[6];
    float c1 = op[1] + op[4] + op[7];
    float c2 = op[2] + op[5] + op[8];
    float a0 = ap[0], a1 = ap[1], a2 = ap[2];
    uint2 oa;
    oa.x = (unsigned int)f2b(a1 * c2) | ((unsigned int)f2b(a2 * c1) << 16);
    oa.y = (unsigned int)f2b(a2 * c0) | ((unsigned int)f2b(a0 * c2) << 16);
    Ga[i] = oa;
    Gz[i] = (unsigned int)f2b(a0 * c1) | ((unsigned int)f2b(a1 * c0) << 16);
  }
  {
    bool msk = (mk == 0);
    float rb[16];
#pragma unroll
    for (int r = 0; r < 16; ++r) {
      float tt = (dv - (float)r * (20.0f / 15.0f)) * 0.8f;
      rb[r] = __expf(-tt * tt);
    }
#pragma unroll
    for (int l2 = 0; l2 < L_; ++l2) {
      float sv = bm_s[l2];
#pragma unroll
      for (int r = 0; r < 16; ++r) sv += rb[r] * wm_s[l2 * 16 + r];
      db4[(size_t)l2 * BNNc + i] = f2b(msk ? -1e9f : sv);
    }
  }
}

// ---------------------------------------------------------------- fallback singles (small-workspace paths)
__global__ __launch_bounds__(256) void geomb_kernel(const float* __restrict__ ori,
                                                    const float* __restrict__ ad,
                                                    uint2* __restrict__ Ga,
                                                    unsigned int* __restrict__ Gz) {
  size_t i = (size_t)blockIdx.x * 256 + threadIdx.x;
  size_t stride = (size_t)gridDim.x * 256;
  for (; i < BNNc; i += stride) {
    const float* op = ori + i * 9;
    const float* ap = ad + i * 3;
    float c0 = op[0] + op[3] + op[6];
    float c1 = op[1] + op[4] + op[7];
    float c2 = op[2] + op[5] + op[8];
    float a0 = ap[0], a1 = ap[1], a2 = ap[2];
    uint2 oa;
    oa.x = (unsigned int)f2b(a1 * c2) | ((unsigned int)f2b(a2 * c1) << 16);
    oa.y = (unsigned int)f2b(a2 * c0) | ((unsigned int)f2b(a0 * c2) << 16);
    Ga[i] = oa;
    Gz[i] = (unsigned int)f2b(a0 * c1) | ((unsigned int)f2b(a1 * c0) << 16);
  }
}
__global__ __launch_bounds__(256) void rbf4_kernel(const float* __restrict__ dist,
                                                   const int* __restrict__ mask,
                                                   const float* __restrict__ Wmlp,
                                                   const float* __restrict__ bmlp,
                                                   unsigned short* __restrict__ db4) {
  size_t i = (size_t)blockIdx.x * 256 + threadIdx.x;
  size_t stride = (size_t)gridDim.x * 256;
  for (; i < BNNc; i += stride) {
    float dv = dist[i];
    bool msk = (mask[i] == 0);
    float rb[16];
#pragma unroll
    for (int r = 0; r < 16; ++r) {
      float tt = (dv - (float)r * (20.0f / 15.0f)) * 0.8f;
      rb[r] = __expf(-tt * tt);
    }
#pragma unroll
    for (int l2 = 0; l2 < L_; ++l2) {
      float sv = bmlp[l2];
#pragma unroll
      for (int r = 0; r < 16; ++r) sv += rb[r] * Wmlp[l2 * 16 + r];
      db4[(size_t)l2 * BNNc + i] = f2b(msk ? -1e9f : sv);
    }
  }
}
__global__ __launch_bounds__(256) void rbf_kernel(const float* __restrict__ dist,
                                                  const int* __restrict__ mask,
                                                  const float* __restrict__ wm,
                                                  const float* __restrict__ bm,
                                                  unsigned short* __restrict__ dbias) {
  size_t i = (size_t)blockIdx.x * 256 + threadIdx.x;
  size_t stride = (size_t)gridDim.x * 256;
  float w[16];
#pragma unroll
  for (int r = 0; r < 16; ++r) w[r] = wm[r];
  float b0 = bm[0];
  for (; i < BNNc; i += stride) {
    float dv = dist[i];
    float sv = b0;
#pragma unroll
    for (int r = 0; r < 16; ++r) {
      float tt = (dv - (float)r * (20.0f / 15.0f)) * 0.8f;
      sv += __expf(-tt * tt) * w[r];
    }
    dbias[i] = f2b((mask[i] == 0) ? -1e9f : sv);
  }
}

// ---------------------------------------------------------------- layernorm (wave per row, bf16 out), optional fused v3d
template <bool V3D>
__global__ __launch_bounds__(256) void ln_kernel(const float* __restrict__ x,
                                                 const float* __restrict__ g,
                                                 const float* __restrict__ b,
                                                 unsigned short* __restrict__ out,
                                                 const float* __restrict__ W3,
                                                 const float* __restrict__ b3,
                                                 float* __restrict__ v3d) {
  int lane = threadIdx.x & 63, wid = threadIdx.x >> 6;
  int row = blockIdx.x * 4 + wid;
  const float* xp = x + (size_t)row * D_;
  float v[6], s = 0.f, s2 = 0.f;
#pragma unroll
  for (int i = 0; i < 6; ++i) {
    v[i] = xp[lane + i * 64];
    s += v[i]; s2 += v[i] * v[i];
  }
  s = wsum(s); s2 = wsum(s2);
  float mean = s * (1.0f / D_);
  float var = s2 * (1.0f / D_) - mean * mean;
  float rstd = rsqrtf(var + 1e-5f);
  unsigned short* op = out + (size_t)row * D_;
  float a0 = 0.f, a1 = 0.f, a2 = 0.f;
#pragma unroll
  for (int i = 0; i < 6; ++i) {
    int d = lane + i * 64;
    float nv = (v[i] - mean) * rstd * g[d] + b[d];
    op[d] = f2b(nv);
    if (V3D) {
      a0 += nv * W3[d * 3 + 0];
      a1 += nv * W3[d * 3 + 1];
      a2 += nv * W3[d * 3 + 2];
    }
  }
  if (V3D) {
    a0 = wsum(a0); a1 = wsum(a1); a2 = wsum(a2);
    if (lane == 0) {
      v3d[row * 3 + 0] = a0 + b3[0];
      v3d[row * 3 + 1] = a1 + b3[1];
      v3d[row * 3 + 2] = a2 + b3[2];
    }
  }
}

// ---------------------------------------------------------------- bf16 MFMA GEMM v3: double-buffered LDS, 1 barrier/K-step
// Tile: BM=64 x BN=32 x BK=64. EPI 0: qkv (q dense, k/v frag-major); 1: fp32 += ; 2: relu->bf16.
template <int EPI>
__global__ __launch_bounds__(256) void mfma_gemm2(const unsigned short* __restrict__ A, int lda,
                                                  const unsigned short* __restrict__ WT, int ldw,
                                                  const float* __restrict__ bias,
                                                  float* __restrict__ C0, float* __restrict__ C1,
                                                  float* __restrict__ C2, int ldc, int K) {
  __shared__ __align__(16) unsigned short As[2][64 * 72];
  __shared__ __align__(16) unsigned short Bs[2][32 * 72];
  const int t = threadIdx.x;
  const int l = t & 63, w = t >> 6;
  const int lr = l & 15, lk = l >> 4;
  const int n0 = blockIdx.x * 32, m0 = blockIdx.y * 64;
  const int wm = (w & 1) * 32, wn = (w >> 1) * 16;
  const int arow = t >> 3, acol8 = (t & 7) * 8;
  uint4 ra0, ra1, rb;
  const unsigned short* pa0 = A + (size_t)(m0 + arow) * lda + acol8;
  const unsigned short* pa1 = A + (size_t)(m0 + arow + 32) * lda + acol8;
  const unsigned short* pb = WT + (size_t)(n0 + arow) * ldw + acol8;
  ra0 = *reinterpret_cast<const uint4*>(pa0);
  ra1 = *reinterpret_cast<const uint4*>(pa1);
  rb = *reinterpret_cast<const uint4*>(pb);
  f32x4 acc[2] = {};
  int p = 0;
  for (int kt = 0; kt < K; kt += 64) {
    *reinterpret_cast<uint4*>(&As[p][arow * 72 + acol8]) = ra0;
    *reinterpret_cast<uint4*>(&As[p][(arow + 32) * 72 + acol8]) = ra1;
    *reinterpret_cast<uint4*>(&Bs[p][arow * 72 + acol8]) = rb;
    if (kt + 64 < K) {
      ra0 = *reinterpret_cast<const uint4*>(pa0 + kt + 64);
      ra1 = *reinterpret_cast<const uint4*>(pa1 + kt + 64);
      rb = *reinterpret_cast<const uint4*>(pb + kt + 64);
    }
    __syncthreads();
#pragma unroll
    for (int ks = 0; ks < 2; ++ks) {
      bf16x8 av0 = *reinterpret_cast<const bf16x8*>(&As[p][(wm + lr) * 72 + ks * 32 + lk * 8]);
      bf16x8 av1 = *reinterpret_cast<const bf16x8*>(&As[p][(wm + 16 + lr) * 72 + ks * 32 + lk * 8]);
      bf16x8 bv = *reinterpret_cast<const bf16x8*>(&Bs[p][(wn + lr) * 72 + ks * 32 + lk * 8]);
      acc[0] = __builtin_amdgcn_mfma_f32_16x16x32_bf16(av0, bv, acc[0], 0, 0, 0);
      acc[1] = __builtin_amdgcn_mfma_f32_16x16x32_bf16(av1, bv, acc[1], 0, 0, 0);
    }
    p ^= 1;
  }
#pragma unroll
  for (int mi = 0; mi < 2; ++mi)
#pragma unroll
    for (int e = 0; e < 4; ++e) {
      int row = m0 + wm + mi * 16 + lk * 4 + e;
      int col = n0 + wn + lr;
      float v = acc[mi][e] + bias[col];
      if (EPI == 0) {
        if (col < 384) {
          int h = col / 48, hd = col - h * 48;
          ((unsigned short*)C0)[(size_t)row * 512 + h * 64 + hd] = f2b(v * RSCALE);
        } else if (col < 768) {
          int c2 = col - 384;
          int h = c2 / 48, d = c2 - h * 48;
          int b2 = row >> 10, j = row & 1023;
          int jb = j >> 4, jr = j & 15;
          int ks = d >> 5, dd = d & 31;
          size_t fid = (((size_t)(b2 * 64 + jb) * 8 + h) << 1) + ks;
          ((unsigned short*)C1)[fid * 512 + (size_t)(jr + ((dd >> 3) << 4)) * 8 + (d & 7)] = f2b(v);
        } else {
          int d = col - 768;
          int b2 = row >> 10, j = row & 1023;
          int jg = j >> 5, df = d >> 4;
          size_t fid = (size_t)(b2 * 32 + jg) * 24 + df;
          ((unsigned short*)C2)[fid * 512 + (size_t)((d & 15) + (((j & 31) >> 3) << 4)) * 8 + (j & 7)] = f2b(v);
        }
      }
      if (EPI == 1) C0[(size_t)row * ldc + col] += v;
      if (EPI == 2) ((unsigned short*)C0)[(size_t)row * ldc + col] = f2b(fmaxf(v, 0.f));
    }
}

// ---------------------------------------------------------------- MFMA fused attention v8: 512 threads, head-per-wave,
// frag-major K/V, 2 barriers/tile, defer-max THR=8, tile-top prefetch of frame geometry (G, v3d).
template <bool USEG>
__global__ __launch_bounds__(512, 4) void attn16_kernel(
    const unsigned short* __restrict__ qp, const unsigned short* __restrict__ kpf,
    const unsigned short* __restrict__ vf, const unsigned short* __restrict__ db_l,
    const uint2* __restrict__ Ga, const unsigned int* __restrict__ Gz,
    const float* __restrict__ ad, const float* __restrict__ ori,
    const float* __restrict__ v3d,
    unsigned short* __restrict__ pO, float* __restrict__ pM, float* __restrict__ pL,
    float* __restrict__ pF, float* __restrict__ pMg, float* __restrict__ pLg) {
  __shared__ __align__(16) unsigned short pbuf[8 * 16 * 72];  // P bf16 [h][r][72] (wave-local rows)
  __shared__ __align__(16) unsigned short msw[8 * 16 * 68];   // per-head partials bf16; plane 0 reused for merged probs
  __shared__ __align__(16) float dbs[16 * 68];                // dbias tile (f32 after convert)
  __shared__ float fg_s[16];

  const int t = threadIdx.x;
  const int wv = t >> 6, l = t & 63;  // wv = head
  const int lr = l & 15, lk = l >> 4;
  const int sgrp = blockIdx.y;
  const int i0 = blockIdx.x * 16;
  const int b = i0 >> 10, ib = i0 & 1023;
  const int mr = t >> 5, mc = t & 31;  // merged softmax role: 32 threads per row

  const bf16x8 qf0 = *reinterpret_cast<const bf16x8*>(
      qp + (size_t)(i0 + lr) * 512 + wv * 64 + lk * 8);
  const bf16x8 qf1 = *reinterpret_cast<const bf16x8*>(
      qp + (size_t)(i0 + lr) * 512 + wv * 64 + 32 + lk * 8);

  f32x4 Ofr[3] = {};
  float fracc[2][3] = {};
  float m_ph[4], l_ph[4], fhv[4];
#pragma unroll
  for (int e = 0; e < 4; ++e) { m_ph[e] = -INFINITY; l_ph[e] = 0.f; }
  float m_mg = -INFINITY, l_mg = 0.f;

  for (int jt = sgrp * (N_ / NSPLIT); jt < (sgrp + 1) * (N_ / NSPLIT); jt += JT) {
    // ---- tile-top prefetch: frame geometry for THIS tile (consumed at the frame step) ----
    uint2 ga_r0, ga_r1;
    unsigned int gz_r0, gz_r1;
    float w0p = 0.f, w1p = 0.f, w2p = 0.f;
    if (USEG) {
      const float* vp = v3d + (size_t)((b << 10) + jt + l) * 3;
      w0p = vp[0]; w1p = vp[1]; w2p = vp[2];
      size_t pij0 = ((size_t)b * N_ + (ib + wv * 2)) * N_ + jt + l;
      ga_r0 = Ga[pij0];
      gz_r0 = Gz[pij0];
      ga_r1 = Ga[pij0 + N_];
      gz_r1 = Gz[pij0 + N_];
    }
    // ---- Phase 1: stage dbias (bf16 -> f32), QK^T MFMA (coalesced frag loads) ----
    if (t < 128) {
      int r = t >> 3, c4 = t & 7;
      const uint4* src = reinterpret_cast<const uint4*>(
                             db_l + (size_t)b * NNs + (size_t)(ib + r) * N_ + jt) + c4;
      uint4 v = *src;
      float* dp = &dbs[r * 68 + c4 * 8];
      dp[0] = b2f(v.x & 0xffffu); dp[1] = b2f(v.x >> 16);
      dp[2] = b2f(v.y & 0xffffu); dp[3] = b2f(v.y >> 16);
      dp[4] = b2f(v.z & 0xffffu); dp[5] = b2f(v.z >> 16);
      dp[6] = b2f(v.w & 0xffffu); dp[7] = b2f(v.w >> 16);
    }
    f32x4 sc[4];
    {
      const unsigned short* kbase =
          kpf + ((((size_t)(b * 64) + (jt >> 4)) * 8 + wv) * 2 * 64 + l) * 8;
      bf16x8 kf0[4], kf1[4];
#pragma unroll
      for (int nj = 0; nj < 4; ++nj) {
        kf0[nj] = *reinterpret_cast<const bf16x8*>(kbase + (size_t)nj * 16 * 512);
        kf1[nj] = *reinterpret_cast<const bf16x8*>(kbase + (size_t)nj * 16 * 512 + 512);
      }
#pragma unroll
      for (int nj = 0; nj < 4; ++nj) {
        f32x4 acc = {};
        acc = __builtin_amdgcn_mfma_f32_16x16x32_bf16(qf0, kf0[nj], acc, 0, 0, 0);
        acc = __builtin_amdgcn_mfma_f32_16x16x32_bf16(qf1, kf1[nj], acc, 0, 0, 0);
        sc[nj] = acc;
      }
    }
#pragma unroll
    for (int nj = 0; nj < 4; ++nj)
#pragma unroll
      for (int e = 0; e < 4; ++e)
        msw[(wv * 16 + lk * 4 + e) * 68 + nj * 16 + lr] = f2b(sc[nj][e]);
    __syncthreads();
    // ---- Phase 2a: per-head softmax in registers, defer-max THR=8 ----
    bool needO;
    {
      float sv[4][4];
#pragma unroll
      for (int nj = 0; nj < 4; ++nj)
#pragma unroll
        for (int e = 0; e < 4; ++e)
          sv[nj][e] = sc[nj][e] + dbs[(lk * 4 + e) * 68 + nj * 16 + lr];
      float lm[4];
      bool need = false;
#pragma unroll
      for (int e = 0; e < 4; ++e) {
        lm[e] = fmaxf(fmaxf(sv[0][e], sv[1][e]), fmaxf(sv[2][e], sv[3][e]));
        need = need || (lm[e] > m_ph[e] + 8.f);
      }
      needO = __any(need);
      if (needO) {
#pragma unroll
        for (int e = 0; e < 4; ++e) {
          float rm = lm[e];
          rm = fmaxf(rm, __shfl_xor(rm, 1, 64));
          rm = fmaxf(rm, __shfl_xor(rm, 2, 64));
          rm = fmaxf(rm, __shfl_xor(rm, 4, 64));
          rm = fmaxf(rm, __shfl_xor(rm, 8, 64));
          float nm = fmaxf(m_ph[e], rm);
          fhv[e] = __expf(m_ph[e] - nm);
          m_ph[e] = nm;
          l_ph[e] *= fhv[e];
        }
      }
#pragma unroll
      for (int e = 0; e < 4; ++e) {
        float ls = 0.f;
#pragma unroll
        for (int nj = 0; nj < 4; ++nj) {
          float pv = __expf(sv[nj][e] - m_ph[e]);
          sv[nj][e] = pv;
          ls += pv;
        }
        ls += __shfl_xor(ls, 1, 64);
        ls += __shfl_xor(ls, 2, 64);
        ls += __shfl_xor(ls, 4, 64);
        ls += __shfl_xor(ls, 8, 64);
        l_ph[e] += ls;
#pragma unroll
        for (int nj = 0; nj < 4; ++nj)
          pbuf[(wv * 16 + lk * 4 + e) * 72 + nj * 16 + lr] = f2b(sv[nj][e]);
      }
    }
    // ---- Phase 2b: merged softmax (sum 8 bf16 planes + 8*dbias), defer-max ----
    {
      float mv[2];
#pragma unroll
      for (int i = 0; i < 2; ++i) {
        int j = mc + 32 * i;
        float s = 8.f * dbs[mr * 68 + j];
#pragma unroll
        for (int h = 0; h < 8; ++h) s += b2f(msw[(h * 16 + mr) * 68 + j]);
        mv[i] = s;
      }
      float lm2 = fmaxf(mv[0], mv[1]);
      bool needm = __any(lm2 > m_mg + 8.f);
      if (needm) {
        float tmax = lm2;
        tmax = fmaxf(tmax, __shfl_xor(tmax, 1, 64));
        tmax = fmaxf(tmax, __shfl_xor(tmax, 2, 64));
        tmax = fmaxf(tmax, __shfl_xor(tmax, 4, 64));
        tmax = fmaxf(tmax, __shfl_xor(tmax, 8, 64));
        tmax = fmaxf(tmax, __shfl_xor(tmax, 16, 64));
        float nm = fmaxf(m_mg, tmax);
        float f = __expf(m_mg - nm);
        m_mg = nm;
        l_mg *= f;
        if (mc == 0) fg_s[mr] = f;
      } else if (mc == 0) {
        fg_s[mr] = 1.f;
      }
      float lsum = 0.f;
#pragma unroll
      for (int i = 0; i < 2; ++i) {
        mv[i] = __expf(mv[i] - m_mg);
        lsum += mv[i];
        msw[mr * 68 + mc + 32 * i] = f2b(mv[i]);
      }
      lsum += __shfl_xor(lsum, 1, 64);
      lsum += __shfl_xor(lsum, 2, 64);
      lsum += __shfl_xor(lsum, 4, 64);
      lsum += __shfl_xor(lsum, 8, 64);
      lsum += __shfl_xor(lsum, 16, 64);
      l_mg += lsum;
    }
    // ---- Phase 3 (no barrier needed: all reads wave-local): PV MFMA + frame ----
    {
      bf16x8 af0 = *reinterpret_cast<const bf16x8*>(&pbuf[(wv * 16 + lr) * 72 + lk * 8]);
      bf16x8 af1 = *reinterpret_cast<const bf16x8*>(&pbuf[(wv * 16 + lr) * 72 + 32 + lk * 8]);
      const unsigned short* vbase =
          vf + ((((size_t)(b * 32) + (jt >> 5)) * 24 + wv * 3) * 64 + l) * 8;
#pragma unroll
      for (int ni = 0; ni < 3; ++ni) {
        bf16x8 bf0 = *reinterpret_cast<const bf16x8*>(vbase + (size_t)ni * 512);
        bf16x8 bf1 = *reinterpret_cast<const bf16x8*>(vbase + (size_t)(24 + ni) * 512);
        f32x4 o = Ofr[ni];
        if (needO) {
#pragma unroll
          for (int e = 0; e < 4; ++e) o[e] *= fhv[e];
        }
        o = __builtin_amdgcn_mfma_f32_16x16x32_bf16(af0, bf0, o, 0, 0, 0);
        o = __builtin_amdgcn_mfma_f32_16x16x32_bf16(af1, bf1, o, 0, 0, 0);
        Ofr[ni] = o;
      }
    }
    {
      float w0, w1, w2;
      if (USEG) {
        w0 = w0p; w1 = w1p; w2 = w2p;
      } else {
        const float* vp = v3d + (size_t)((b << 10) + jt + l) * 3;
        w0 = vp[0]; w1 = vp[1]; w2 = vp[2];
      }
#pragma unroll
      for (int e = 0; e < 2; ++e) {
        int r = wv * 2 + e;
        float pm = b2f(msw[r * 68 + l]);
        float d0, d1, d2;
        if (USEG) {
          uint2 ga = (e == 0) ? ga_r0 : ga_r1;
          unsigned int gz = (e == 0) ? gz_r0 : gz_r1;
          float g0 = b2f(ga.x & 0xffffu), g1 = b2f(ga.x >> 16);
          float g2 = b2f(ga.y & 0xffffu), g3 = b2f(ga.y >> 16);
          float g4 = b2f(gz & 0xffffu), g5 = b2f(gz >> 16);
          d0 = g0 * w2 - g1 * w1;
          d1 = g2 * w0 - g3 * w2;
          d2 = g4 * w1 - g5 * w0;
        } else {
          size_t pij = ((size_t)b * N_ + (ib + r)) * N_ + jt + l;
          const float* op = ori + pij * 9;
          const float* ap = ad + pij * 3;
          float a0 = ap[0], a1 = ap[1], a2 = ap[2];
          float u0 = (op[0] + op[3] + op[6]) * w0;
          float u1 = (op[1] + op[4] + op[7]) * w1;
          float u2 = (op[2] + op[5] + op[8]) * w2;
          d0 = a1 * u2 - a2 * u1; d1 = a2 * u0 - a0 * u2; d2 = a0 * u1 - a1 * u0;
        }
        float fgr = fg_s[r];
        fracc[e][0] = fracc[e][0] * fgr + pm * d0;
        fracc[e][1] = fracc[e][1] * fgr + pm * d1;
        fracc[e][2] = fracc[e][2] * fgr + pm * d2;
      }
    }
    __syncthreads();
  }
  // ---- epilogue: write split partials (O in bf16) ----
  const size_t rowb = (size_t)sgrp * BN_ + i0;
#pragma unroll
  for (int ni = 0; ni < 3; ++ni)
#pragma unroll
    for (int e = 0; e < 4; ++e)
      pO[(rowb + lk * 4 + e) * D_ + wv * 48 + ni * 16 + lr] = f2b(Ofr[ni][e]);
#pragma unroll
  for (int e = 0; e < 2; ++e)
#pragma unroll
    for (int c = 0; c < 3; ++c) {
      float v = wsum(fracc[e][c]);
      if (l == 0) pF[(rowb + wv * 2 + e) * 3 + c] = v;
    }
  if (lr == 0) {
#pragma unroll
    for (int e = 0; e < 4; ++e) {
      pM[(rowb + lk * 4 + e) * H_ + wv] = m_ph[e];
      pL[(rowb + lk * 4 + e) * H_ + wv] = l_ph[e];
    }
  }
  if (mc == 0) { pMg[rowb + mr] = m_mg; pLg[rowb + mr] = l_mg; }
}

// ---------------------------------------------------------------- combine split partials -> cc (bf16, padded)
constexpr int QR = 8;
__global__ __launch_bounds__(256) void combine_kernel(
    const unsigned short* __restrict__ pO, const float* __restrict__ pM,
    const float* __restrict__ pL, const float* __restrict__ pF,
    const float* __restrict__ pMg, const float* __restrict__ pLg,
    unsigned short* __restrict__ cc) {
  __shared__ float sc[QR][H_][NSPLIT];
  __shared__ float scg[QR][NSPLIT];
  int t = threadIdx.x;
  int i0 = blockIdx.x * QR;
  if (t < QR * H_) {
    int r = t >> 3, h = t & 7;
    size_t row = i0 + r;
    float ms[NSPLIT], ls[NSPLIT], m = -INFINITY;
#pragma unroll
    for (int s2 = 0; s2 < NSPLIT; ++s2) {
      ms[s2] = pM[((size_t)s2 * BN_ + row) * H_ + h];
      ls[s2] = pL[((size_t)s2 * BN_ + row) * H_ + h];
      m = fmaxf(m, ms[s2]);
    }
    float L = 0.f, e[NSPLIT];
#pragma unroll
    for (int s2 = 0; s2 < NSPLIT; ++s2) { e[s2] = __expf(ms[s2] - m); L += ls[s2] * e[s2]; }
    float invL = 1.0f / L;
#pragma unroll
    for (int s2 = 0; s2 < NSPLIT; ++s2) sc[r][h][s2] = e[s2] * invL;
  } else if (t < QR * H_ + QR) {
    int r = t - QR * H_;
    size_t row = i0 + r;
    float ms[NSPLIT], ls[NSPLIT], m = -INFINITY;
#pragma unroll
    for (int s2 = 0; s2 < NSPLIT; ++s2) {
      ms[s2] = pMg[(size_t)s2 * BN_ + row];
      ls[s2] = pLg[(size_t)s2 * BN_ + row];
      m = fmaxf(m, ms[s2]);
    }
    float L = 0.f, e[NSPLIT];
#pragma unroll
    for (int s2 = 0; s2 < NSPLIT; ++s2) { e[s2] = __expf(ms[s2] - m); L += ls[s2] * e[s2]; }
    float inv = 1.0f / (L * (float)N_);
#pragma unroll
    for (int s2 = 0; s2 < NSPLIT; ++s2) scg[r][s2] = e[s2] * inv;
  }
  __syncthreads();
  // coalesced: d fastest within each row
#pragma unroll
  for (int r = 0; r < QR; ++r) {
    size_t row = i0 + r;
    for (int d = t; d < D_; d += 256) {
      int h = d / HD_;
      float o = 0.f;
#pragma unroll
      for (int s2 = 0; s2 < NSPLIT; ++s2)
        o += b2f(pO[((size_t)s2 * BN_ + row) * D_ + d]) * sc[r][h][s2];
      cc[row * CCLD + d] = f2b(o);
    }
  }
  if (t < QR * 3) {
    int r = t / 3, c = t % 3;
    size_t row = i0 + r;
    float F = 0.f;
#pragma unroll
    for (int s2 = 0; s2 < NSPLIT; ++s2) F += pF[((size_t)s2 * BN_ + row) * 3 + c] * scg[r][s2];
    cc[row * CCLD + 384 + c] = f2b(F);
  }
  for (int idx = t; idx < QR * (CCLD - 387); idx += 256) {
    int r = idx / (CCLD - 387), col = 387 + idx % (CCLD - 387);
    cc[(size_t)(i0 + r) * CCLD + col] = 0;
  }
}

// ---------------------------------------------------------------- launch
extern "C" void kernel_launch(void* const* d_in, const int* in_sizes, int n_in,
                              void* d_out, int out_size, void* d_ws, size_t ws_size,
                              hipStream_t stream) {
  const float* x_rigid = (const float*)d_in[0];
  const float* ad      = (const float*)d_in[1];
  const float* ori     = (const float*)d_in[2];
  const float* dist    = (const float*)d_in[3];
  const int*   mask    = (const int*)d_in[4];
  const float* Wq  = (const float*)d_in[5];
  const float* bq  = (const float*)d_in[6];
  const float* Wk  = (const float*)d_in[7];
  const float* bk  = (const float*)d_in[8];
  const float* Wv  = (const float*)d_in[9];
  const float* bv  = (const float*)d_in[10];
  const float* W3  = (const float*)d_in[11];
  const float* b3  = (const float*)d_in[12];
  const float* Wmlp = (const float*)d_in[13];
  const float* bmlp = (const float*)d_in[14];
  const float* Wfc  = (const float*)d_in[15];
  const float* bfc  = (const float*)d_in[16];
  const float* Wff1 = (const float*)d_in[17];
  const float* bff1 = (const float*)d_in[18];
  const float* Wff2 = (const float*)d_in[19];
  const float* bff2 = (const float*)d_in[20];
  const float* ln1g = (const float*)d_in[21];
  const float* ln1b = (const float*)d_in[22];
  const float* ln2g = (const float*)d_in[23];
  const float* ln2b = (const float*)d_in[24];

  float* x = (float*)d_out;

  size_t off = 0;
  auto alloc = [&](size_t bytes) -> void* {
    void* r = (char*)d_ws + off;
    off = (off + bytes + 255) & ~(size_t)255;
    return r;
  };
  unsigned short* WqkvT = (unsigned short*)alloc((size_t)L_ * 1152 * D_ * 2);
  unsigned short* WfcT  = (unsigned short*)alloc((size_t)L_ * D_ * CCLD * 2);
  unsigned short* Wff1T = (unsigned short*)alloc((size_t)L_ * DFF2 * D_ * 2);
  unsigned short* Wff2T = (unsigned short*)alloc((size_t)L_ * D_ * DFF2 * 2);
  float* bqkv = (float*)alloc((size_t)L_ * 1152 * 4);
  unsigned short* qp  = (unsigned short*)alloc((size_t)BN_ * 512 * 2);
  unsigned short* kpf = (unsigned short*)alloc((size_t)2048 * 64 * 8 * 2);  // 2 MB frag-major K
  unsigned short* vf  = (unsigned short*)alloc((size_t)1536 * 64 * 8 * 2);  // 1.5 MB frag-major V
  unsigned short* hb  = (unsigned short*)alloc((size_t)BN_ * D_ * 2);
  unsigned short* h2  = (unsigned short*)alloc((size_t)BN_ * D_ * 2);
  unsigned short* cc  = (unsigned short*)alloc((size_t)BN_ * CCLD * 2);
  unsigned short* ffb = (unsigned short*)alloc((size_t)BN_ * DFF2 * 2);
  float* v3 = (float*)alloc((size_t)BN_ * 3 * 4);
  unsigned short* pO = (unsigned short*)alloc((size_t)NSPLIT * BN_ * D_ * 2);
  float* pM = (float*)alloc((size_t)NSPLIT * BN_ * H_ * 4);
  float* pL = (float*)alloc((size_t)NSPLIT * BN_ * H_ * 4);
  float* pF = (float*)alloc((size_t)NSPLIT * BN_ * 3 * 4);
  float* pMg = (float*)alloc((size_t)NSPLIT * BN_ * 4);
  float* pLg = (float*)alloc((size_t)NSPLIT * BN_ * 4);
  size_t need_base = off;
  // G (bf16, 12 B/pair) has priority over db4 (bigger per-layer savings)
  uint2* Ga = (uint2*)alloc(BNNc * 8);
  unsigned int* Gz = (unsigned int*)alloc(BNNc * 4);
  bool useG = (off <= ws_size);
  size_t off_g = useG ? off : need_base;
  off = off_g;
  unsigned short* db4 = (unsigned short*)alloc((size_t)L_ * BNNc * 2);
  bool use4 = (off <= ws_size);
  unsigned short* db1 = nullptr;
  if (!use4) {
    off = off_g;
    db1 = (unsigned short*)alloc(BNNc * 2);
    if (off > ws_size) return;  // insufficient scratch
  }
  if (ws_size < need_base) return;

  // one-time: unified weight pack (6 transposes in 1 dispatch) + misc (copy/padzero/bias)
  pack_all_kernel<<<dim3(984, 1, L_), 256, 0, stream>>>(Wq, Wk, Wv, Wfc, Wff1, Wff2,
                                                        WqkvT, WfcT, Wff1T, Wff2T);
  misc_kernel<<<5138, 256, 0, stream>>>(x, x_rigid, qp, kpf, bq, bk, bv, bqkv);
  if (useG && use4) {
    precomp_kernel<<<8192, 256, 0, stream>>>(ori, ad, dist, mask, Wmlp, bmlp, Ga, Gz, db4);
  } else {
    if (useG) geomb_kernel<<<4096, 256, 0, stream>>>(ori, ad, Ga, Gz);
    if (use4) rbf4_kernel<<<4096, 256, 0, stream>>>(dist, mask, Wmlp, bmlp, db4);
  }

  for (int l = 0; l < L_; ++l) {
    const unsigned short* db_l = use4 ? (db4 + (size_t)l * BNNc) : db1;
    if (!use4) rbf_kernel<<<4096, 256, 0, stream>>>(dist, mask, Wmlp + l * 16, bmlp + l, db1);
    ln_kernel<true><<<BN_ / 4, 256, 0, stream>>>(x, ln1g + l * D_, ln1b + l * D_, hb,
                                                 W3 + (size_t)l * D_ * 3, b3 + l * 3, v3);
    mfma_gemm2<0><<<dim3(36, 32), 256, 0, stream>>>(
        hb, D_, WqkvT + (size_t)l * 1152 * D_, D_, bqkv + l * 1152,
        (float*)qp, (float*)kpf, (float*)vf, 0, D_);
    if (useG)
      attn16_kernel<true><<<dim3(BN_ / 16, NSPLIT), 512, 0, stream>>>(
          qp, kpf, vf, db_l, Ga, Gz, ad, ori, v3, pO, pM, pL, pF, pMg, pLg);
    else
      attn16_kernel<false><<<dim3(BN_ / 16, NSPLIT), 512, 0, stream>>>(
          qp, kpf, vf, db_l, Ga, Gz, ad, ori, v3, pO, pM, pL, pF, pMg, pLg);
    combine_kernel<<<BN_ / QR, 256, 0, stream>>>(pO, pM, pL, pF, pMg, pLg, cc);
    mfma_gemm2<1><<<dim3(12, 32), 256, 0, stream>>>(
        cc, CCLD, WfcT + (size_t)l * D_ * CCLD, CCLD, bfc + l * D_, x, nullptr, nullptr, D_, CCLD);
    ln_kernel<false><<<BN_ / 4, 256, 0, stream>>>(x, ln2g + l * D_, ln2b + l * D_, h2,
                                                  nullptr, nullptr, nullptr);
    mfma_gemm2<2><<<dim3(16, 32), 256, 0, stream>>>(
        h2, D_, Wff1T + (size_t)l * DFF2 * D_, D_, bff1 + l * DFF2, (float*)ffb, nullptr, nullptr,
        DFF2, D_);
    mfma_gemm2<1><<<dim3(12, 32), 256, 0, stream>>>(
        ffb, DFF2, Wff2T + (size_t)l * D_ * DFF2, DFF2, bff2 + l * D_, x, nullptr, nullptr, D_,
        DFF2);
  }
}